// Round 9
// baseline (11501.543 us; speedup 1.0000x reference)
//
#include <hip/hip_runtime.h>
#include <cstddef>
#include <cstdint>

#define BN_EPS 1e-5f

typedef float f4 __attribute__((ext_vector_type(4)));

// ---------------------------------------------------------------------------
// Weight transpose: W[27][CIN][COUT] -> Wt[k][ci/4][co][4] so a lane (=co)
// loads 4 consecutive ci as one coalesced dwordx4.
// ---------------------------------------------------------------------------
template<int CIN, int COUT>
__global__ __launch_bounds__(256)
void wtrans(const float* __restrict__ W, float* __restrict__ Wt)
{
    const int t = blockIdx.x * 256 + threadIdx.x;
    constexpr int TOTAL = 27 * (CIN / 4) * COUT;
    if (t >= TOTAL) return;
    const int co = t % COUT;
    const int rest = t / COUT;
    const int c4 = rest % (CIN / 4);
    const int k  = rest / (CIN / 4);
    f4 v;
    #pragma unroll
    for (int u = 0; u < 4; ++u)
        v[u] = W[((size_t)k * CIN + c4 * 4 + u) * COUT + co];
    *(f4*)(Wt + (size_t)t * 4) = v;
}

// ---------------------------------------------------------------------------
// Pair compaction: for each k, append all valid (out_j, in_m) into per-k
// segments jArr/mArr[k*Nout ...], counts in cnt[k*16] (64B-padded counters;
// ~27 atomics per 256-row block -- contention-free, round-3 lesson).
// ---------------------------------------------------------------------------
__global__ __launch_bounds__(256)
void build_pairs(const int* __restrict__ map, int Nout,
                 int* __restrict__ jArr, int* __restrict__ mArr,
                 int* __restrict__ cnt)
{
    const int tid  = threadIdx.x;
    const int lane = tid & 63;
    const int wave = tid >> 6;
    const int j    = blockIdx.x * 256 + tid;

    __shared__ int wcnt[27][4];
    __shared__ int woff[27][4];

    // pass 1: per-wave counts
    for (int k = 0; k < 27; ++k) {
        const int v = (j < Nout) ? map[(size_t)k * Nout + j] : -1;
        const unsigned long long bal = __ballot(v >= 0);
        if (lane == 0) wcnt[k][wave] = (int)__popcll(bal);
    }
    __syncthreads();
    if (tid < 27) {
        const int c0 = wcnt[tid][0], c1 = wcnt[tid][1];
        const int c2 = wcnt[tid][2], c3 = wcnt[tid][3];
        const int base = atomicAdd(&cnt[tid * 16], c0 + c1 + c2 + c3);
        woff[tid][0] = base;
        woff[tid][1] = base + c0;
        woff[tid][2] = base + c0 + c1;
        woff[tid][3] = base + c0 + c1 + c2;
    }
    __syncthreads();
    // pass 2: write pairs (maps are L2-hot from pass 1)
    for (int k = 0; k < 27; ++k) {
        const int v = (j < Nout) ? map[(size_t)k * Nout + j] : -1;
        const unsigned long long bal = __ballot(v >= 0);
        const int rank = (int)__popcll(bal & ((1ull << lane) - 1ull));
        if (v >= 0) {
            const int pos = woff[k][wave] + rank;
            jArr[(size_t)k * Nout + pos] = j;
            mArr[(size_t)k * Nout + pos] = v;
        }
    }
}

// ---------------------------------------------------------------------------
// Pair-compacted sparse conv, COUT in {64,128}. Persistent waves sweep the 27
// per-k pair segments; each wave-step handles P=8 VALID pairs of one k (vs
// ~1.3 of 8 in the round-8 gather form). Inner structure = the proven round-8
// winner: wave-uniform x row pointers (readfirstlane -> batched s_loads, 8
// rows x 8ch in flight), Wt dwordx4 weights shared across the 8 pairs.
// Output scatter via fp32 atomicAdd (distinct addresses; out zero-initialized
// by memset). x may be a concat of xA (CINA ch) and xB (CIN-CINA ch).
// ---------------------------------------------------------------------------
template<int CIN, int CINA, int COUT>
__global__ __launch_bounds__(256)
void sconv_pairs(const float* __restrict__ xA, const float* __restrict__ xB,
                 const float* __restrict__ Wt,
                 const int* __restrict__ jArr, const int* __restrict__ mArr,
                 const int* __restrict__ cnt, int Nout, int nwaves,
                 float* __restrict__ out, const float* __restrict__ zrow)
{
    constexpr int CINB = CIN - CINA;
    constexpr int CPL  = COUT / 64;
    constexpr int P    = 8;
    const int lane = threadIdx.x & 63;
    const int wv   = blockIdx.x * 4 + (threadIdx.x >> 6);

    for (int k = 0; k < 27; ++k) {
        const int nk = cnt[k * 16];
        const int nseg = (nk + P - 1) / P;
        const float* Wk = Wt + (size_t)k * CIN * COUT;
        const int* jBase = jArr + (size_t)k * Nout;
        const int* mBase = mArr + (size_t)k * Nout;

        for (int s = wv; s < nseg; s += nwaves) {
            const int p0 = s * P;

            int jj[P];
            const float* pA[P];
            const float* pB[P];
            #pragma unroll
            for (int r = 0; r < P; ++r) {
                const int p = p0 + r;
                const bool valid = (p < nk);           // wave-uniform
                int jv = valid ? jBase[p] : -1;
                int mv = valid ? mBase[p] : 0;
                jj[r] = __builtin_amdgcn_readfirstlane(jv);
                mv    = __builtin_amdgcn_readfirstlane(mv);
                pA[r] = valid ? (xA + (size_t)mv * CINA) : zrow;
                if constexpr (CINB > 0)
                    pB[r] = valid ? (xB + (size_t)mv * CINB) : zrow;
            }

            float acc[P][CPL];
            #pragma unroll
            for (int r = 0; r < P; ++r)
                #pragma unroll
                for (int c = 0; c < CPL; ++c) acc[r][c] = 0.f;

            #pragma unroll
            for (int t = 0; t < CIN / 8; ++t) {
                const int ci = t * 8;
                // W tile: 2 dwordx4 per CPL, shared by all 8 pairs
                f4 w0[CPL], w1[CPL];
                #pragma unroll
                for (int c = 0; c < CPL; ++c) {
                    w0[c] = *(const f4*)(Wk + ((size_t)(2 * t) * COUT
                                               + c * 64 + lane) * 4);
                    w1[c] = *(const f4*)(Wk + ((size_t)(2 * t + 1) * COUT
                                               + c * 64 + lane) * 4);
                }
                // batched uniform x s_loads -- every row USEFUL here
                f4 xv0[P], xv1[P];
                #pragma unroll
                for (int r = 0; r < P; ++r) {
                    const float* p;
                    if constexpr (CINB > 0)
                        p = (ci < CINA) ? (pA[r] + ci) : (pB[r] + (ci - CINA));
                    else
                        p = pA[r] + ci;
                    xv0[r] = *(const f4*)p;
                    xv1[r] = *(const f4*)(p + 4);
                }
                // unguarded FMA (tail rows read zrow -> contribute 0)
                #pragma unroll
                for (int r = 0; r < P; ++r)
                    #pragma unroll
                    for (int u = 0; u < 4; ++u)
                        #pragma unroll
                        for (int c = 0; c < CPL; ++c) {
                            acc[r][c] = fmaf(xv0[r][u], w0[c][u], acc[r][c]);
                            acc[r][c] = fmaf(xv1[r][u], w1[c][u], acc[r][c]);
                        }
            }

            #pragma unroll
            for (int r = 0; r < P; ++r) {
                if (jj[r] >= 0) {                      // wave-uniform
                    #pragma unroll
                    for (int c = 0; c < CPL; ++c)
                        atomicAdd(&out[(size_t)jj[r] * COUT + c * 64 + lane],
                                  acc[r][c]);
                }
            }
        }
    }
}

// ---------------------------------------------------------------------------
// conv0: CIN=16, COUT=32. One row per half-wave; block 256 = 8 rows.
// ---------------------------------------------------------------------------
__global__ __launch_bounds__(256)
void sconv0(const float* __restrict__ x, const float* __restrict__ Wt,
            const int* __restrict__ map, int N, float* __restrict__ out,
            const float* __restrict__ zrow)
{
    const int tid  = threadIdx.x;
    const int lane = tid & 63;
    const int l32  = tid & 31;
    const int co   = l32;
    const int j    = blockIdx.x * 8 + (tid >> 5);

    int mk = (l32 < 27 && j < N) ? map[(size_t)l32 * N + j] : -1;

    float a0 = 0.f, a1 = 0.f, a2 = 0.f, a3 = 0.f;
    for (int k = 0; k < 27; ++k) {
        const int m = __shfl(mk, (lane & 32) + k);
        if (__ballot(m >= 0) == 0ull) continue;
        const float* xr = (m >= 0) ? (x + (size_t)m * 16) : zrow;
        const float* wk = Wt + (size_t)k * 16 * 32;
        f4 w0 = *(const f4*)(wk + (0 * 32 + co) * 4);
        f4 w1 = *(const f4*)(wk + (1 * 32 + co) * 4);
        f4 w2 = *(const f4*)(wk + (2 * 32 + co) * 4);
        f4 w3 = *(const f4*)(wk + (3 * 32 + co) * 4);
        f4 x0 = *(const f4*)(xr);
        f4 x1 = *(const f4*)(xr + 4);
        f4 x2 = *(const f4*)(xr + 8);
        f4 x3 = *(const f4*)(xr + 12);
        #pragma unroll
        for (int u = 0; u < 4; ++u) {
            a0 = fmaf(x0[u], w0[u], a0);
            a1 = fmaf(x1[u], w1[u], a1);
            a2 = fmaf(x2[u], w2[u], a2);
            a3 = fmaf(x3[u], w3[u], a3);
        }
    }
    if (j < N) out[(size_t)j * 32 + co] = (a0 + a1) + (a2 + a3);
}

// ---------------------------------------------------------------------------
// conv0t: x = concat(d1[*,64], s1[*,32]), COUT=2. 32 lanes cooperate per row.
// ---------------------------------------------------------------------------
__global__ __launch_bounds__(256)
void sconv0t(const float* __restrict__ d1, const float* __restrict__ s1,
             const float* __restrict__ W /*[27,96,2]*/,
             const int* __restrict__ map, int N, float* __restrict__ out,
             const float* __restrict__ zrow)
{
    const int tid  = threadIdx.x;
    const int lane = tid & 63;
    const int l32  = tid & 31;
    const int j    = blockIdx.x * 8 + (tid >> 5);

    int mk = (l32 < 27 && j < N) ? map[(size_t)l32 * N + j] : -1;

    float a0 = 0.f, a1 = 0.f;
    for (int k = 0; k < 27; ++k) {
        const int m = __shfl(mk, (lane & 32) + k);
        if (__ballot(m >= 0) == 0ull) continue;
        const float* p1 = (m >= 0) ? (d1 + (size_t)m * 64) : zrow;
        const float* p2 = (m >= 0) ? (s1 + (size_t)m * 32) : zrow;
        const float* w = W + (size_t)k * 96 * 2;
        const float x0 = p1[l32];
        const float x1 = p1[l32 + 32];
        const float x2 = p2[l32];
        a0 = fmaf(x0, w[l32 * 2 + 0], a0);
        a1 = fmaf(x0, w[l32 * 2 + 1], a1);
        a0 = fmaf(x1, w[(l32 + 32) * 2 + 0], a0);
        a1 = fmaf(x1, w[(l32 + 32) * 2 + 1], a1);
        a0 = fmaf(x2, w[(l32 + 64) * 2 + 0], a0);
        a1 = fmaf(x2, w[(l32 + 64) * 2 + 1], a1);
    }
    #pragma unroll
    for (int off = 1; off < 32; off <<= 1) {
        a0 += __shfl_xor(a0, off, 32);
        a1 += __shfl_xor(a1, off, 32);
    }
    if (l32 == 0 && j < N) {
        out[(size_t)j * 2 + 0] = a0;
        out[(size_t)j * 2 + 1] = a1;
    }
}

// ---------------------------------------------------------------------------
// BN pass 1: per-channel sum and sum-of-squares -> atomicAdd into sums[2*C]
// ---------------------------------------------------------------------------
template<int C>
__global__ __launch_bounds__(256)
void bn_reduce_kernel(const float* __restrict__ x, int N,
                      float* __restrict__ sums)
{
    constexpr int RG = 256 / C;
    const int tid = threadIdx.x;
    const int c   = tid % C;
    const int rg  = tid / C;
    float s = 0.f, s2 = 0.f;
    for (int j = blockIdx.x * RG + rg; j < N; j += gridDim.x * RG) {
        const float v = x[(size_t)j * C + c];
        s += v;
        s2 += v * v;
    }
    __shared__ float sh[2 * 256];
    sh[tid] = s;
    sh[256 + tid] = s2;
    __syncthreads();
    for (int stride = 128; stride >= C; stride >>= 1) {
        if (tid < stride) {
            sh[tid] += sh[tid + stride];
            sh[256 + tid] += sh[256 + tid + stride];
        }
        __syncthreads();
    }
    if (tid < C) {
        atomicAdd(&sums[c], sh[tid]);
        atomicAdd(&sums[C + c], sh[256 + tid]);
    }
}

// ---------------------------------------------------------------------------
// BN pass 2: x = relu((x - mu) * rsqrt(var + eps) * g + b), in place
// ---------------------------------------------------------------------------
template<int C>
__global__ __launch_bounds__(256)
void bn_apply_kernel(float* __restrict__ x, int N,
                     const float* __restrict__ sums,
                     const float* __restrict__ g, const float* __restrict__ b)
{
    const int tid = blockIdx.x * blockDim.x + threadIdx.x;
    const int c = tid % C;
    const float invN = 1.0f / (float)N;
    const float mean = sums[c] * invN;
    float var = sums[C + c] * invN - mean * mean;
    var = fmaxf(var, 0.f);
    const float sc = g[c] * rsqrtf(var + BN_EPS);
    const float sh = b[c] - mean * sc;
    const int rows_stride = (gridDim.x * blockDim.x) / C;
    for (int j = tid / C; j < N; j += rows_stride) {
        const size_t i = (size_t)j * C + c;
        const float v = fmaf(x[i], sc, sh);
        x[i] = v > 0.f ? v : 0.f;
    }
}

// ---------------------------------------------------------------------------
extern "C" void kernel_launch(void* const* d_in, const int* in_sizes, int n_in,
                              void* d_out, int out_size, void* d_ws, size_t ws_size,
                              hipStream_t stream)
{
    const float* feats = (const float*)d_in[0];
    const float* W0  = (const float*)d_in[1];
    const float* g0  = (const float*)d_in[2];
    const float* b0  = (const float*)d_in[3];
    const float* W1  = (const float*)d_in[4];
    const float* g1  = (const float*)d_in[5];
    const float* b1  = (const float*)d_in[6];
    const float* W2  = (const float*)d_in[7];
    const float* g2  = (const float*)d_in[8];
    const float* b2  = (const float*)d_in[9];
    const float* W2t = (const float*)d_in[10];
    const float* g2t = (const float*)d_in[11];
    const float* b2t = (const float*)d_in[12];
    const float* W1t = (const float*)d_in[13];
    const float* g1t = (const float*)d_in[14];
    const float* b1t = (const float*)d_in[15];
    const float* W0t = (const float*)d_in[16];
    const int* map0  = (const int*)d_in[17];
    const int* map1  = (const int*)d_in[18];
    const int* map2  = (const int*)d_in[19];
    const int* map2t = (const int*)d_in[20];
    const int* map1t = (const int*)d_in[21];
    const int* map0t = (const int*)d_in[22];

    const int N0 = in_sizes[0] / 16;
    const int N1 = in_sizes[18] / 27;
    const int N2 = in_sizes[19] / 27;

    float* ws = (float*)d_ws;
    float* y0 = ws;                      // [N0,32]  s1
    float* y1 = y0 + (size_t)N0 * 32;    // [N1,64]  s2
    float* y2 = y1 + (size_t)N1 * 64;    // [N2,128] s4
    float* y3 = y2 + (size_t)N2 * 128;   // [N1,64]  d2
    float* y4 = y3 + (size_t)N1 * 64;    // [N0,64]  d1
    float* sums  = y4 + (size_t)N0 * 64; // BN accumulators (704 floats)
    float* sums0 = sums;        // 2*32
    float* sums1 = sums + 64;   // 2*64
    float* sums2 = sums + 192;  // 2*128
    float* sums3 = sums + 448;  // 2*64
    float* sums4 = sums + 576;  // 2*64
    float* zrow  = sums + 704;  // 128 zeroed floats
    int*   cntA  = (int*)(zrow + 128);   // 4 x 27 x 16 padded counters
    int*   cntB  = cntA + 27 * 16;
    int*   cntC  = cntB + 27 * 16;
    int*   cntD  = cntC + 27 * 16;
    float* Wt0  = (float*)(cntD + 27 * 16);     // 27*16*32
    float* Wt1  = Wt0 + 27 * 16 * 32;           // 27*32*64
    float* Wt2  = Wt1 + 27 * 32 * 64;           // 27*64*128
    float* Wt2t = Wt2 + 27 * 64 * 128;          // 27*128*64
    float* Wt1t = Wt2t + 27 * 128 * 64;         // 27*128*64
    int*   jArr = (int*)(Wt1t + 27 * 128 * 64); // 27*N0 ints
    int*   mArr = jArr + (size_t)27 * N0;       // 27*N0 ints

    // zero: sums + zrow + counters (one small memset), then out buffers that
    // receive atomic scatter
    hipMemsetAsync(sums, 0, (704 + 128 + 4 * 27 * 16) * sizeof(float), stream);
    hipMemsetAsync(y1, 0, (size_t)N1 * 64 * sizeof(float), stream);
    hipMemsetAsync(y2, 0, (size_t)N2 * 128 * sizeof(float), stream);
    hipMemsetAsync(y3, 0, (size_t)N1 * 64 * sizeof(float), stream);
    hipMemsetAsync(y4, 0, (size_t)N0 * 64 * sizeof(float), stream);

    // weight transposes (tiny)
    wtrans<16, 32><<<(27 * 4 * 32 + 255) / 256, 256, 0, stream>>>(W0, Wt0);
    wtrans<32, 64><<<(27 * 8 * 64 + 255) / 256, 256, 0, stream>>>(W1, Wt1);
    wtrans<64, 128><<<(27 * 16 * 128 + 255) / 256, 256, 0, stream>>>(W2, Wt2);
    wtrans<128, 64><<<(27 * 32 * 64 + 255) / 256, 256, 0, stream>>>(W2t, Wt2t);
    wtrans<128, 64><<<(27 * 32 * 64 + 255) / 256, 256, 0, stream>>>(W1t, Wt1t);

    const int NBLK = 2048, NW = NBLK * 4;

    // block0: feats[N0,16] -> y0[N0,32]  (gather form; writes every row)
    sconv0<<<(N0 + 7) / 8, 256, 0, stream>>>(feats, Wt0, map0, N0, y0, zrow);
    bn_reduce_kernel<32><<<256, 256, 0, stream>>>(y0, N0, sums0);
    bn_apply_kernel<32><<<512, 256, 0, stream>>>(y0, N0, sums0, g0, b0);

    // block1: s1[N0,32] -> y1[N1,64]
    build_pairs<<<(N1 + 255) / 256, 256, 0, stream>>>(map1, N1, jArr, mArr, cntA);
    sconv_pairs<32, 32, 64><<<NBLK, 256, 0, stream>>>(
        y0, nullptr, Wt1, jArr, mArr, cntA, N1, NW, y1, zrow);
    bn_reduce_kernel<64><<<256, 256, 0, stream>>>(y1, N1, sums1);
    bn_apply_kernel<64><<<512, 256, 0, stream>>>(y1, N1, sums1, g1, b1);

    // block2: s2[N1,64] -> y2[N2,128]
    build_pairs<<<(N2 + 255) / 256, 256, 0, stream>>>(map2, N2, jArr, mArr, cntB);
    sconv_pairs<64, 64, 128><<<NBLK, 256, 0, stream>>>(
        y1, nullptr, Wt2, jArr, mArr, cntB, N2, NW, y2, zrow);
    bn_reduce_kernel<128><<<256, 256, 0, stream>>>(y2, N2, sums2);
    bn_apply_kernel<128><<<512, 256, 0, stream>>>(y2, N2, sums2, g2, b2);

    // block2_tr: s4[N2,128] -> y3[N1,64]
    build_pairs<<<(N1 + 255) / 256, 256, 0, stream>>>(map2t, N1, jArr, mArr, cntC);
    sconv_pairs<128, 128, 64><<<NBLK, 256, 0, stream>>>(
        y2, nullptr, Wt2t, jArr, mArr, cntC, N1, NW, y3, zrow);
    bn_reduce_kernel<64><<<256, 256, 0, stream>>>(y3, N1, sums3);
    bn_apply_kernel<64><<<512, 256, 0, stream>>>(y3, N1, sums3, g2t, b2t);

    // block1_tr: concat(d2,s2)[N1,128] -> y4[N0,64]
    build_pairs<<<(N0 + 255) / 256, 256, 0, stream>>>(map1t, N0, jArr, mArr, cntD);
    sconv_pairs<128, 64, 64><<<NBLK, 256, 0, stream>>>(
        y3, y1, Wt1t, jArr, mArr, cntD, N0, NW, y4, zrow);
    bn_reduce_kernel<64><<<256, 256, 0, stream>>>(y4, N0, sums4);
    bn_apply_kernel<64><<<512, 256, 0, stream>>>(y4, N0, sums4, g1t, b1t);

    // block0_tr: concat(d1,s1)[N0,96] -> out[N0,2]
    sconv0t<<<(N0 + 7) / 8, 256, 0, stream>>>(y4, y0, W0t, map0t, N0,
                                              (float*)d_out, zrow);
}

// Round 11
// 1488.026 us; speedup vs baseline: 7.7294x; 7.7294x over previous
//
#include <hip/hip_runtime.h>
#include <cstddef>
#include <cstdint>

#define BN_EPS 1e-5f

typedef float f4 __attribute__((ext_vector_type(4)));
typedef _Float16 h2 __attribute__((ext_vector_type(2)));
typedef _Float16 h8 __attribute__((ext_vector_type(8)));

#if defined(__has_builtin)
#if __has_builtin(__builtin_amdgcn_fdot2)
#define DOT2(a, b, c) __builtin_amdgcn_fdot2((a), (b), (c), false)
#endif
#endif
#ifndef DOT2
#define DOT2(a, b, c) fmaf((float)(a)[1], (float)(b)[1], fmaf((float)(a)[0], (float)(b)[0], (c)))
#endif

// ---------------------------------------------------------------------------
// fp32 weight transpose (sconv0 only): W[27][CIN][COUT] -> Wt[k][ci/4][co][4]
// ---------------------------------------------------------------------------
template<int CIN, int COUT>
__global__ __launch_bounds__(256)
void wtrans(const float* __restrict__ W, float* __restrict__ Wt)
{
    const int t = blockIdx.x * 256 + threadIdx.x;
    constexpr int TOTAL = 27 * (CIN / 4) * COUT;
    if (t >= TOTAL) return;
    const int co = t % COUT;
    const int rest = t / COUT;
    const int c4 = rest % (CIN / 4);
    const int k  = rest / (CIN / 4);
    f4 v;
    #pragma unroll
    for (int u = 0; u < 4; ++u)
        v[u] = W[((size_t)k * CIN + c4 * 4 + u) * COUT + co];
    *(f4*)(Wt + (size_t)t * 4) = v;
}

// ---------------------------------------------------------------------------
// f16 weight transpose: W[27][CIN][COUT] -> Wh[k][ci/8][co][8] (16B per co
// per tile: 8 consecutive input channels, ready for h8 load + dot2).
// ---------------------------------------------------------------------------
template<int CIN, int COUT>
__global__ __launch_bounds__(256)
void wtrans_h(const float* __restrict__ W, _Float16* __restrict__ Wh)
{
    const int t = blockIdx.x * 256 + threadIdx.x;
    constexpr int TOTAL = 27 * (CIN / 8) * COUT;
    if (t >= TOTAL) return;
    const int co = t % COUT;
    const int rest = t / COUT;
    const int t8 = rest % (CIN / 8);
    const int k  = rest / (CIN / 8);
    h8 v;
    #pragma unroll
    for (int u = 0; u < 8; ++u)
        v[u] = (_Float16)W[((size_t)k * CIN + t8 * 8 + u) * COUT + co];
    *(h8*)(Wh + (size_t)t * 8) = v;
}

// ---------------------------------------------------------------------------
// f16 sparse conv, COUT in {64,128}. Round-8 proven structure (ctz active-k
// loop, wave-uniform zrow-redirected x pointers -> unguarded batched s_loads,
// guarded MAC blocks) with f16 data: one 16B s_load = 8 x-channels, one 16B
// vmem = 8 w-channels, v_dot2_f32_f16 = 2 MACs/inst with fp32 accumulate.
// h2 extraction via pointer reinterpret (shufflevector needs literal idx).
// ---------------------------------------------------------------------------
template<int CIN, int CINA, int COUT>
__global__ __launch_bounds__(256)
void sconv_big_h(const _Float16* __restrict__ xA, const _Float16* __restrict__ xB,
                 const _Float16* __restrict__ Wh, const int* __restrict__ map,
                 int Nout, _Float16* __restrict__ out,
                 const _Float16* __restrict__ zrh)
{
    constexpr int CINB = CIN - CINA;
    constexpr int CPL  = COUT / 64;
    constexpr int R    = 8;
    constexpr int NT   = CIN / 8;
    const int lane = threadIdx.x & 63;
    const int wave = threadIdx.x >> 6;
    const int row0 = (blockIdx.x * 4 + wave) * R;

    int mk[R];
    bool anyv = false;
    #pragma unroll
    for (int r = 0; r < R; ++r) {
        const int j = row0 + r;
        mk[r] = (lane < 27 && j < Nout) ? map[(size_t)lane * Nout + j] : -1;
        anyv |= (mk[r] >= 0);
    }
    unsigned long long act = __ballot(anyv);

    float acc[R][CPL];
    #pragma unroll
    for (int r = 0; r < R; ++r)
        #pragma unroll
        for (int c = 0; c < CPL; ++c) acc[r][c] = 0.f;

    while (act) {
        const int k = (int)__builtin_ctzll(act);
        act &= act - 1;

        int m[R];
        const _Float16* pA[R];
        const _Float16* pB[R];
        #pragma unroll
        for (int r = 0; r < R; ++r) {
            m[r] = __builtin_amdgcn_readlane(mk[r], k);   // uniform SGPR
            const bool v = (m[r] >= 0);
            pA[r] = v ? (xA + (size_t)m[r] * CINA) : zrh;  // uniform cselect
            if constexpr (CINB > 0)
                pB[r] = v ? (xB + (size_t)m[r] * CINB) : zrh;
        }

        const _Float16* Wk = Wh + (size_t)k * NT * COUT * 8;

        #pragma unroll
        for (int t = 0; t < NT; ++t) {
            const int ci = t * 8;
            // ---- W tile: one 16B load per CPL (8 channels) ----
            h8 wv[CPL];
            #pragma unroll
            for (int c = 0; c < CPL; ++c)
                wv[c] = *(const h8*)(Wk + ((size_t)t * COUT + c * 64 + lane) * 8);

            // ---- unguarded batched x s_loads: one 16B per row ----
            h8 xv[R];
            #pragma unroll
            for (int r = 0; r < R; ++r) {
                const _Float16* p;
                if constexpr (CINB > 0)
                    p = (ci < CINA) ? (pA[r] + ci) : (pB[r] + (ci - CINA));
                else
                    p = pA[r] + ci;
                xv[r] = *(const h8*)p;
            }

            // ---- guarded dot2 blocks (wave-uniform scalar branches) ----
            #pragma unroll
            for (int r = 0; r < R; ++r) {
                if (m[r] >= 0) {
                    const h2* xp = (const h2*)&xv[r];
                    #pragma unroll
                    for (int q = 0; q < 4; ++q) {
                        const h2 xa = xp[q];
                        #pragma unroll
                        for (int c = 0; c < CPL; ++c) {
                            const h2* wp = (const h2*)&wv[c];
                            acc[r][c] = DOT2(xa, wp[q], acc[r][c]);
                        }
                    }
                }
            }
        }
    }

    #pragma unroll
    for (int r = 0; r < R; ++r) {
        const int j = row0 + r;
        if (j < Nout) {
            #pragma unroll
            for (int c = 0; c < CPL; ++c)
                out[(size_t)j * COUT + c * 64 + lane] = (_Float16)acc[r][c];
        }
    }
}

// ---------------------------------------------------------------------------
// conv0: CIN=16 (fp32 input feats), COUT=32 -> half output. One row per
// half-wave; fp32 Wt dwordx4 loads; zrow-unguarded x.
// ---------------------------------------------------------------------------
__global__ __launch_bounds__(256)
void sconv0(const float* __restrict__ x, const float* __restrict__ Wt,
            const int* __restrict__ map, int N, _Float16* __restrict__ out,
            const float* __restrict__ zrow)
{
    const int tid  = threadIdx.x;
    const int lane = tid & 63;
    const int l32  = tid & 31;
    const int co   = l32;
    const int j    = blockIdx.x * 8 + (tid >> 5);

    int mk = (l32 < 27 && j < N) ? map[(size_t)l32 * N + j] : -1;

    float a0 = 0.f, a1 = 0.f, a2 = 0.f, a3 = 0.f;
    for (int k = 0; k < 27; ++k) {
        const int m = __shfl(mk, (lane & 32) + k);
        if (__ballot(m >= 0) == 0ull) continue;
        const float* xr = (m >= 0) ? (x + (size_t)m * 16) : zrow;
        const float* wk = Wt + (size_t)k * 16 * 32;
        f4 w0 = *(const f4*)(wk + (0 * 32 + co) * 4);
        f4 w1 = *(const f4*)(wk + (1 * 32 + co) * 4);
        f4 w2 = *(const f4*)(wk + (2 * 32 + co) * 4);
        f4 w3 = *(const f4*)(wk + (3 * 32 + co) * 4);
        f4 x0 = *(const f4*)(xr);
        f4 x1 = *(const f4*)(xr + 4);
        f4 x2 = *(const f4*)(xr + 8);
        f4 x3 = *(const f4*)(xr + 12);
        #pragma unroll
        for (int u = 0; u < 4; ++u) {
            a0 = fmaf(x0[u], w0[u], a0);
            a1 = fmaf(x1[u], w1[u], a1);
            a2 = fmaf(x2[u], w2[u], a2);
            a3 = fmaf(x3[u], w3[u], a3);
        }
    }
    if (j < N) out[(size_t)j * 32 + co] = (_Float16)((a0 + a1) + (a2 + a3));
}

// ---------------------------------------------------------------------------
// conv0t: x = concat(d1[*,64] half, s1[*,32] half), COUT=2, fp32 W & output.
// ---------------------------------------------------------------------------
__global__ __launch_bounds__(256)
void sconv0t(const _Float16* __restrict__ d1, const _Float16* __restrict__ s1,
             const float* __restrict__ W /*[27,96,2]*/,
             const int* __restrict__ map, int N, float* __restrict__ out,
             const _Float16* __restrict__ zrh)
{
    const int tid  = threadIdx.x;
    const int lane = tid & 63;
    const int l32  = tid & 31;
    const int j    = blockIdx.x * 8 + (tid >> 5);

    int mk = (l32 < 27 && j < N) ? map[(size_t)l32 * N + j] : -1;

    float a0 = 0.f, a1 = 0.f;
    for (int k = 0; k < 27; ++k) {
        const int m = __shfl(mk, (lane & 32) + k);
        if (__ballot(m >= 0) == 0ull) continue;
        const _Float16* p1 = (m >= 0) ? (d1 + (size_t)m * 64) : zrh;
        const _Float16* p2 = (m >= 0) ? (s1 + (size_t)m * 32) : zrh;
        const float* w = W + (size_t)k * 96 * 2;
        const float x0 = (float)p1[l32];
        const float x1 = (float)p1[l32 + 32];
        const float x2 = (float)p2[l32];
        a0 = fmaf(x0, w[l32 * 2 + 0], a0);
        a1 = fmaf(x0, w[l32 * 2 + 1], a1);
        a0 = fmaf(x1, w[(l32 + 32) * 2 + 0], a0);
        a1 = fmaf(x1, w[(l32 + 32) * 2 + 1], a1);
        a0 = fmaf(x2, w[(l32 + 64) * 2 + 0], a0);
        a1 = fmaf(x2, w[(l32 + 64) * 2 + 1], a1);
    }
    #pragma unroll
    for (int off = 1; off < 32; off <<= 1) {
        a0 += __shfl_xor(a0, off, 32);
        a1 += __shfl_xor(a1, off, 32);
    }
    if (l32 == 0 && j < N) {
        out[(size_t)j * 2 + 0] = a0;
        out[(size_t)j * 2 + 1] = a1;
    }
}

// ---------------------------------------------------------------------------
// BN pass 1 on half tensors: per-channel sum/sumsq -> atomicAdd sums[2*C]
// ---------------------------------------------------------------------------
template<int C>
__global__ __launch_bounds__(256)
void bn_reduce_h(const _Float16* __restrict__ x, int N,
                 float* __restrict__ sums)
{
    constexpr int RG = 256 / C;
    const int tid = threadIdx.x;
    const int c   = tid % C;
    const int rg  = tid / C;
    float s = 0.f, s2 = 0.f;
    for (int j = blockIdx.x * RG + rg; j < N; j += gridDim.x * RG) {
        const float v = (float)x[(size_t)j * C + c];
        s += v;
        s2 += v * v;
    }
    __shared__ float sh[2 * 256];
    sh[tid] = s;
    sh[256 + tid] = s2;
    __syncthreads();
    for (int stride = 128; stride >= C; stride >>= 1) {
        if (tid < stride) {
            sh[tid] += sh[tid + stride];
            sh[256 + tid] += sh[256 + tid + stride];
        }
        __syncthreads();
    }
    if (tid < C) {
        atomicAdd(&sums[c], sh[tid]);
        atomicAdd(&sums[C + c], sh[256 + tid]);
    }
}

// ---------------------------------------------------------------------------
// BN pass 2 on half tensors: x = relu((x-mu)*rsqrt(var+eps)*g + b), in place
// ---------------------------------------------------------------------------
template<int C>
__global__ __launch_bounds__(256)
void bn_apply_h(_Float16* __restrict__ x, int N,
                const float* __restrict__ sums,
                const float* __restrict__ g, const float* __restrict__ b)
{
    const int tid = blockIdx.x * blockDim.x + threadIdx.x;
    const int c = tid % C;
    const float invN = 1.0f / (float)N;
    const float mean = sums[c] * invN;
    float var = sums[C + c] * invN - mean * mean;
    var = fmaxf(var, 0.f);
    const float sc = g[c] * rsqrtf(var + BN_EPS);
    const float sh = b[c] - mean * sc;
    const int rows_stride = (gridDim.x * blockDim.x) / C;
    for (int j = tid / C; j < N; j += rows_stride) {
        const size_t i = (size_t)j * C + c;
        const float v = fmaf((float)x[i], sc, sh);
        x[i] = (_Float16)(v > 0.f ? v : 0.f);
    }
}

// ---------------------------------------------------------------------------
extern "C" void kernel_launch(void* const* d_in, const int* in_sizes, int n_in,
                              void* d_out, int out_size, void* d_ws, size_t ws_size,
                              hipStream_t stream)
{
    const float* feats = (const float*)d_in[0];
    const float* W0  = (const float*)d_in[1];
    const float* g0  = (const float*)d_in[2];
    const float* b0  = (const float*)d_in[3];
    const float* W1  = (const float*)d_in[4];
    const float* g1  = (const float*)d_in[5];
    const float* b1  = (const float*)d_in[6];
    const float* W2  = (const float*)d_in[7];
    const float* g2  = (const float*)d_in[8];
    const float* b2  = (const float*)d_in[9];
    const float* W2t = (const float*)d_in[10];
    const float* g2t = (const float*)d_in[11];
    const float* b2t = (const float*)d_in[12];
    const float* W1t = (const float*)d_in[13];
    const float* g1t = (const float*)d_in[14];
    const float* b1t = (const float*)d_in[15];
    const float* W0t = (const float*)d_in[16];
    const int* map0  = (const int*)d_in[17];
    const int* map1  = (const int*)d_in[18];
    const int* map2  = (const int*)d_in[19];
    const int* map2t = (const int*)d_in[20];
    const int* map1t = (const int*)d_in[21];
    const int* map0t = (const int*)d_in[22];

    const int N0 = in_sizes[0] / 16;
    const int N1 = in_sizes[18] / 27;
    const int N2 = in_sizes[19] / 27;

    float* ws = (float*)d_ws;
    float* sums  = ws;          // 704 floats of BN accumulators
    float* sums0 = sums;        // 2*32
    float* sums1 = sums + 64;   // 2*64
    float* sums2 = sums + 192;  // 2*128
    float* sums3 = sums + 448;  // 2*64
    float* sums4 = sums + 576;  // 2*64
    float* zrow  = sums + 704;  // 128 zeroed floats (fp32 & f16 zero rows)
    float* Wt0   = zrow + 128;  // 27*16*32 fp32
    _Float16* hb = (_Float16*)(Wt0 + 27 * 16 * 32);
    _Float16* Wh1  = hb;                        // 27*32*64
    _Float16* Wh2  = Wh1 + 27 * 32 * 64;        // 27*64*128
    _Float16* Wh2t = Wh2 + 27 * 64 * 128;       // 27*128*64
    _Float16* Wh1t = Wh2t + 27 * 128 * 64;      // 27*128*64
    _Float16* y0 = Wh1t + 27 * 128 * 64;        // [N0,32]  s1
    _Float16* y1 = y0 + (size_t)N0 * 32;        // [N1,64]  s2
    _Float16* y2 = y1 + (size_t)N1 * 64;        // [N2,128] s4
    _Float16* y3 = y2 + (size_t)N2 * 128;       // [N1,64]  d2
    _Float16* y4 = y3 + (size_t)N1 * 64;        // [N0,64]  d1
    const _Float16* zrh = (const _Float16*)zrow;

    (void)hipMemsetAsync(sums, 0, (704 + 128) * sizeof(float), stream);

    // weight transposes (tiny)
    wtrans<16, 32><<<(27 * 4 * 32 + 255) / 256, 256, 0, stream>>>(W0, Wt0);
    wtrans_h<32, 64><<<(27 * 4 * 64 + 255) / 256, 256, 0, stream>>>(W1, Wh1);
    wtrans_h<64, 128><<<(27 * 8 * 128 + 255) / 256, 256, 0, stream>>>(W2, Wh2);
    wtrans_h<128, 64><<<(27 * 16 * 64 + 255) / 256, 256, 0, stream>>>(W2t, Wh2t);
    wtrans_h<128, 64><<<(27 * 16 * 64 + 255) / 256, 256, 0, stream>>>(W1t, Wh1t);

    // block0: feats[N0,16] fp32 -> y0[N0,32] half
    sconv0<<<(N0 + 7) / 8, 256, 0, stream>>>(feats, Wt0, map0, N0, y0, zrow);
    bn_reduce_h<32><<<256, 256, 0, stream>>>(y0, N0, sums0);
    bn_apply_h<32><<<512, 256, 0, stream>>>(y0, N0, sums0, g0, b0);

    // block1: s1[N0,32] -> y1[N1,64]
    sconv_big_h<32, 32, 64><<<(N1 + 31) / 32, 256, 0, stream>>>(
        y0, nullptr, Wh1, map1, N1, y1, zrh);
    bn_reduce_h<64><<<256, 256, 0, stream>>>(y1, N1, sums1);
    bn_apply_h<64><<<512, 256, 0, stream>>>(y1, N1, sums1, g1, b1);

    // block2: s2[N1,64] -> y2[N2,128]
    sconv_big_h<64, 64, 128><<<(N2 + 31) / 32, 256, 0, stream>>>(
        y1, nullptr, Wh2, map2, N2, y2, zrh);
    bn_reduce_h<128><<<256, 256, 0, stream>>>(y2, N2, sums2);
    bn_apply_h<128><<<512, 256, 0, stream>>>(y2, N2, sums2, g2, b2);

    // block2_tr: s4[N2,128] -> y3[N1,64]
    sconv_big_h<128, 128, 64><<<(N1 + 31) / 32, 256, 0, stream>>>(
        y2, nullptr, Wh2t, map2t, N1, y3, zrh);
    bn_reduce_h<64><<<256, 256, 0, stream>>>(y3, N1, sums3);
    bn_apply_h<64><<<512, 256, 0, stream>>>(y3, N1, sums3, g2t, b2t);

    // block1_tr: concat(d2,s2)[N1,128] -> y4[N0,64]
    sconv_big_h<128, 64, 64><<<(N0 + 31) / 32, 256, 0, stream>>>(
        y3, y1, Wh1t, map1t, N0, y4, zrh);
    bn_reduce_h<64><<<256, 256, 0, stream>>>(y4, N0, sums4);
    bn_apply_h<64><<<512, 256, 0, stream>>>(y4, N0, sums4, g1t, b1t);

    // block0_tr: concat(d1,s1)[N0,96] -> out[N0,2] fp32
    sconv0t<<<(N0 + 7) / 8, 256, 0, stream>>>(y4, y0, W0t, map0t, N0,
                                              (float*)d_out, zrh);
}

// Round 12
// 1400.459 us; speedup vs baseline: 8.2127x; 1.0625x over previous
//
#include <hip/hip_runtime.h>
#include <cstddef>
#include <cstdint>

#define BN_EPS 1e-5f

typedef float f4 __attribute__((ext_vector_type(4)));
typedef _Float16 h2 __attribute__((ext_vector_type(2)));
typedef _Float16 h8 __attribute__((ext_vector_type(8)));

#if defined(__has_builtin)
#if __has_builtin(__builtin_amdgcn_fdot2)
#define DOT2(a, b, c) __builtin_amdgcn_fdot2((a), (b), (c), false)
#endif
#endif
#ifndef DOT2
#define DOT2(a, b, c) fmaf((float)(a)[1], (float)(b)[1], fmaf((float)(a)[0], (float)(b)[0], (c)))
#endif

// ---------------------------------------------------------------------------
// fp32 weight transpose (sconv0 only): W[27][CIN][COUT] -> Wt[k][ci/4][co][4]
// ---------------------------------------------------------------------------
template<int CIN, int COUT>
__global__ __launch_bounds__(256)
void wtrans(const float* __restrict__ W, float* __restrict__ Wt)
{
    const int t = blockIdx.x * 256 + threadIdx.x;
    constexpr int TOTAL = 27 * (CIN / 4) * COUT;
    if (t >= TOTAL) return;
    const int co = t % COUT;
    const int rest = t / COUT;
    const int c4 = rest % (CIN / 4);
    const int k  = rest / (CIN / 4);
    f4 v;
    #pragma unroll
    for (int u = 0; u < 4; ++u)
        v[u] = W[((size_t)k * CIN + c4 * 4 + u) * COUT + co];
    *(f4*)(Wt + (size_t)t * 4) = v;
}

// ---------------------------------------------------------------------------
// f16 weight transpose: W[27][CIN][COUT] -> Wh[k][ci/8][co][8]
// ---------------------------------------------------------------------------
template<int CIN, int COUT>
__global__ __launch_bounds__(256)
void wtrans_h(const float* __restrict__ W, _Float16* __restrict__ Wh)
{
    const int t = blockIdx.x * 256 + threadIdx.x;
    constexpr int TOTAL = 27 * (CIN / 8) * COUT;
    if (t >= TOTAL) return;
    const int co = t % COUT;
    const int rest = t / COUT;
    const int t8 = rest % (CIN / 8);
    const int k  = rest / (CIN / 8);
    h8 v;
    #pragma unroll
    for (int u = 0; u < 8; ++u)
        v[u] = (_Float16)W[((size_t)k * CIN + t8 * 8 + u) * COUT + co];
    *(h8*)(Wh + (size_t)t * 8) = v;
}

// ---------------------------------------------------------------------------
// Map transpose: map[27][Nout] -> mapT[Nout][32] (k-major per row, -1 pad in
// cols 27..31). One wave then fetches a row's entire neighbor list as a
// single coalesced 128B read instead of 27 scattered lines.
// ---------------------------------------------------------------------------
__global__ __launch_bounds__(256)
void map_transpose(const int* __restrict__ map, int Nout,
                   int* __restrict__ mapT)
{
    __shared__ int s[256][28];
    const int tid  = threadIdx.x;
    const int base = blockIdx.x * 256;
    const int j    = base + tid;
    for (int k = 0; k < 27; ++k)
        s[tid][k] = (j < Nout) ? map[(size_t)k * Nout + j] : -1;
    __syncthreads();
    for (int i = tid; i < 256 * 32; i += 256) {
        const int r = i >> 5, c = i & 31;
        if (base + r < Nout)
            mapT[(size_t)(base + r) * 32 + c] = (c < 27) ? s[r][c] : -1;
    }
}

// ---------------------------------------------------------------------------
// R=1 f16 sparse conv, COUT in {64,128}: ONE WAVE = ONE OUTPUT ROW.
// Rationale (round-12): per-row slot work = K_union(R); R=1 minimizes it
// (1.25 vs 8.5 steps/row at R=8 -- 6.8x less x-load/setup work) while W
// amortization degrades only 18% (all L1-hit). Every proven element kept:
// whole-wave row => m wave-uniform => scalar batched x s_loads; static
// unrolled ci tiles; ctz active-k loop; dot2 fp32-accumulate.
// ---------------------------------------------------------------------------
template<int CIN, int CINA, int COUT>
__global__ __launch_bounds__(256)
void sconv_r1(const _Float16* __restrict__ xA, const _Float16* __restrict__ xB,
              const _Float16* __restrict__ Wh, const int* __restrict__ mapT,
              int Nout, _Float16* __restrict__ out)
{
    constexpr int CINB = CIN - CINA;
    constexpr int CPL  = COUT / 64;
    constexpr int NT   = CIN / 8;
    const int lane = threadIdx.x & 63;
    const int j    = blockIdx.x * 4 + (threadIdx.x >> 6);

    int mk = -1;
    if (j < Nout && lane < 32) mk = mapT[(size_t)j * 32 + lane];
    unsigned long long act = __ballot(mk >= 0);   // bits 0..26 only

    float acc[CPL];
    #pragma unroll
    for (int c = 0; c < CPL; ++c) acc[c] = 0.f;

    while (act) {
        const int k = (int)__builtin_ctzll(act);
        act &= act - 1;
        const int m = __builtin_amdgcn_readlane(mk, k);   // uniform SGPR

        const _Float16* pA = xA + (size_t)m * CINA;
        const _Float16* pB = nullptr;
        if constexpr (CINB > 0) pB = xB + (size_t)m * CINB;

        const _Float16* Wk = Wh + (size_t)k * NT * COUT * 8;

        #pragma unroll
        for (int t = 0; t < NT; ++t) {
            const int ci = t * 8;
            // W tile: one 16B VMEM per CPL (lane = co)
            h8 wv[CPL];
            #pragma unroll
            for (int c = 0; c < CPL; ++c)
                wv[c] = *(const h8*)(Wk + ((size_t)t * COUT + c * 64 + lane) * 8);
            // x tile: one 16B scalar load (wave-uniform address)
            const _Float16* p;
            if constexpr (CINB > 0)
                p = (ci < CINA) ? (pA + ci) : (pB + (ci - CINA));
            else
                p = pA + ci;
            const h8 xv = *(const h8*)p;
            const h2* xp = (const h2*)&xv;
            #pragma unroll
            for (int q = 0; q < 4; ++q) {
                #pragma unroll
                for (int c = 0; c < CPL; ++c) {
                    const h2* wp = (const h2*)&wv[c];
                    acc[c] = DOT2(xp[q], wp[q], acc[c]);
                }
            }
        }
    }

    if (j < Nout) {
        #pragma unroll
        for (int c = 0; c < CPL; ++c)
            out[(size_t)j * COUT + c * 64 + lane] = (_Float16)acc[c];
    }
}

// ---------------------------------------------------------------------------
// conv0: CIN=16 (fp32 input feats), COUT=32 -> half output. One row per
// half-wave; fp32 Wt dwordx4 loads; zrow-unguarded x.
// ---------------------------------------------------------------------------
__global__ __launch_bounds__(256)
void sconv0(const float* __restrict__ x, const float* __restrict__ Wt,
            const int* __restrict__ map, int N, _Float16* __restrict__ out,
            const float* __restrict__ zrow)
{
    const int tid  = threadIdx.x;
    const int lane = tid & 63;
    const int l32  = tid & 31;
    const int co   = l32;
    const int j    = blockIdx.x * 8 + (tid >> 5);

    int mk = (l32 < 27 && j < N) ? map[(size_t)l32 * N + j] : -1;

    float a0 = 0.f, a1 = 0.f, a2 = 0.f, a3 = 0.f;
    for (int k = 0; k < 27; ++k) {
        const int m = __shfl(mk, (lane & 32) + k);
        if (__ballot(m >= 0) == 0ull) continue;
        const float* xr = (m >= 0) ? (x + (size_t)m * 16) : zrow;
        const float* wk = Wt + (size_t)k * 16 * 32;
        f4 w0 = *(const f4*)(wk + (0 * 32 + co) * 4);
        f4 w1 = *(const f4*)(wk + (1 * 32 + co) * 4);
        f4 w2 = *(const f4*)(wk + (2 * 32 + co) * 4);
        f4 w3 = *(const f4*)(wk + (3 * 32 + co) * 4);
        f4 x0 = *(const f4*)(xr);
        f4 x1 = *(const f4*)(xr + 4);
        f4 x2 = *(const f4*)(xr + 8);
        f4 x3 = *(const f4*)(xr + 12);
        #pragma unroll
        for (int u = 0; u < 4; ++u) {
            a0 = fmaf(x0[u], w0[u], a0);
            a1 = fmaf(x1[u], w1[u], a1);
            a2 = fmaf(x2[u], w2[u], a2);
            a3 = fmaf(x3[u], w3[u], a3);
        }
    }
    if (j < N) out[(size_t)j * 32 + co] = (_Float16)((a0 + a1) + (a2 + a3));
}

// ---------------------------------------------------------------------------
// conv0t: x = concat(d1[*,64] half, s1[*,32] half), COUT=2, fp32 W & output.
// ---------------------------------------------------------------------------
__global__ __launch_bounds__(256)
void sconv0t(const _Float16* __restrict__ d1, const _Float16* __restrict__ s1,
             const float* __restrict__ W /*[27,96,2]*/,
             const int* __restrict__ map, int N, float* __restrict__ out,
             const _Float16* __restrict__ zrh)
{
    const int tid  = threadIdx.x;
    const int lane = tid & 63;
    const int l32  = tid & 31;
    const int j    = blockIdx.x * 8 + (tid >> 5);

    int mk = (l32 < 27 && j < N) ? map[(size_t)l32 * N + j] : -1;

    float a0 = 0.f, a1 = 0.f;
    for (int k = 0; k < 27; ++k) {
        const int m = __shfl(mk, (lane & 32) + k);
        if (__ballot(m >= 0) == 0ull) continue;
        const _Float16* p1 = (m >= 0) ? (d1 + (size_t)m * 64) : zrh;
        const _Float16* p2 = (m >= 0) ? (s1 + (size_t)m * 32) : zrh;
        const float* w = W + (size_t)k * 96 * 2;
        const float x0 = (float)p1[l32];
        const float x1 = (float)p1[l32 + 32];
        const float x2 = (float)p2[l32];
        a0 = fmaf(x0, w[l32 * 2 + 0], a0);
        a1 = fmaf(x0, w[l32 * 2 + 1], a1);
        a0 = fmaf(x1, w[(l32 + 32) * 2 + 0], a0);
        a1 = fmaf(x1, w[(l32 + 32) * 2 + 1], a1);
        a0 = fmaf(x2, w[(l32 + 64) * 2 + 0], a0);
        a1 = fmaf(x2, w[(l32 + 64) * 2 + 1], a1);
    }
    #pragma unroll
    for (int off = 1; off < 32; off <<= 1) {
        a0 += __shfl_xor(a0, off, 32);
        a1 += __shfl_xor(a1, off, 32);
    }
    if (l32 == 0 && j < N) {
        out[(size_t)j * 2 + 0] = a0;
        out[(size_t)j * 2 + 1] = a1;
    }
}

// ---------------------------------------------------------------------------
// BN pass 1 on half tensors: per-channel sum/sumsq -> atomicAdd sums[2*C]
// ---------------------------------------------------------------------------
template<int C>
__global__ __launch_bounds__(256)
void bn_reduce_h(const _Float16* __restrict__ x, int N,
                 float* __restrict__ sums)
{
    constexpr int RG = 256 / C;
    const int tid = threadIdx.x;
    const int c   = tid % C;
    const int rg  = tid / C;
    float s = 0.f, s2 = 0.f;
    for (int j = blockIdx.x * RG + rg; j < N; j += gridDim.x * RG) {
        const float v = (float)x[(size_t)j * C + c];
        s += v;
        s2 += v * v;
    }
    __shared__ float sh[2 * 256];
    sh[tid] = s;
    sh[256 + tid] = s2;
    __syncthreads();
    for (int stride = 128; stride >= C; stride >>= 1) {
        if (tid < stride) {
            sh[tid] += sh[tid + stride];
            sh[256 + tid] += sh[256 + tid + stride];
        }
        __syncthreads();
    }
    if (tid < C) {
        atomicAdd(&sums[c], sh[tid]);
        atomicAdd(&sums[C + c], sh[256 + tid]);
    }
}

// ---------------------------------------------------------------------------
// BN pass 2 on half tensors: x = relu((x-mu)*rsqrt(var+eps)*g + b), in place
// ---------------------------------------------------------------------------
template<int C>
__global__ __launch_bounds__(256)
void bn_apply_h(_Float16* __restrict__ x, int N,
                const float* __restrict__ sums,
                const float* __restrict__ g, const float* __restrict__ b)
{
    const int tid = blockIdx.x * blockDim.x + threadIdx.x;
    const int c = tid % C;
    const float invN = 1.0f / (float)N;
    const float mean = sums[c] * invN;
    float var = sums[C + c] * invN - mean * mean;
    var = fmaxf(var, 0.f);
    const float sc = g[c] * rsqrtf(var + BN_EPS);
    const float sh = b[c] - mean * sc;
    const int rows_stride = (gridDim.x * blockDim.x) / C;
    for (int j = tid / C; j < N; j += rows_stride) {
        const size_t i = (size_t)j * C + c;
        const float v = fmaf((float)x[i], sc, sh);
        x[i] = (_Float16)(v > 0.f ? v : 0.f);
    }
}

// ---------------------------------------------------------------------------
extern "C" void kernel_launch(void* const* d_in, const int* in_sizes, int n_in,
                              void* d_out, int out_size, void* d_ws, size_t ws_size,
                              hipStream_t stream)
{
    const float* feats = (const float*)d_in[0];
    const float* W0  = (const float*)d_in[1];
    const float* g0  = (const float*)d_in[2];
    const float* b0  = (const float*)d_in[3];
    const float* W1  = (const float*)d_in[4];
    const float* g1  = (const float*)d_in[5];
    const float* b1  = (const float*)d_in[6];
    const float* W2  = (const float*)d_in[7];
    const float* g2  = (const float*)d_in[8];
    const float* b2  = (const float*)d_in[9];
    const float* W2t = (const float*)d_in[10];
    const float* g2t = (const float*)d_in[11];
    const float* b2t = (const float*)d_in[12];
    const float* W1t = (const float*)d_in[13];
    const float* g1t = (const float*)d_in[14];
    const float* b1t = (const float*)d_in[15];
    const float* W0t = (const float*)d_in[16];
    const int* map0  = (const int*)d_in[17];
    const int* map1  = (const int*)d_in[18];
    const int* map2  = (const int*)d_in[19];
    const int* map2t = (const int*)d_in[20];
    const int* map1t = (const int*)d_in[21];
    const int* map0t = (const int*)d_in[22];

    const int N0 = in_sizes[0] / 16;
    const int N1 = in_sizes[18] / 27;
    const int N2 = in_sizes[19] / 27;

    float* ws = (float*)d_ws;
    float* sums  = ws;          // 704 floats of BN accumulators
    float* sums0 = sums;        // 2*32
    float* sums1 = sums + 64;   // 2*64
    float* sums2 = sums + 192;  // 2*128
    float* sums3 = sums + 448;  // 2*64
    float* sums4 = sums + 576;  // 2*64
    float* zrow  = sums + 704;  // 128 zeroed floats (fp32 & f16 zero rows)
    float* Wt0   = zrow + 128;  // 27*16*32 fp32
    _Float16* hb = (_Float16*)(Wt0 + 27 * 16 * 32);
    _Float16* Wh1  = hb;                        // 27*32*64
    _Float16* Wh2  = Wh1 + 27 * 32 * 64;        // 27*64*128
    _Float16* Wh2t = Wh2 + 27 * 64 * 128;       // 27*128*64
    _Float16* Wh1t = Wh2t + 27 * 128 * 64;      // 27*128*64
    _Float16* y0 = Wh1t + 27 * 128 * 64;        // [N0,32]  s1
    _Float16* y1 = y0 + (size_t)N0 * 32;        // [N1,64]  s2
    _Float16* y2 = y1 + (size_t)N1 * 64;        // [N2,128] s4
    _Float16* y3 = y2 + (size_t)N2 * 128;       // [N1,64]  d2
    _Float16* y4 = y3 + (size_t)N1 * 64;        // [N0,64]  d1
    int* mapT = (int*)(y4 + (size_t)N0 * 64);   // [Nmax,32] transposed map
    const _Float16* zrh = (const _Float16*)zrow;

    (void)hipMemsetAsync(sums, 0, (704 + 128) * sizeof(float), stream);

    // weight transposes (tiny)
    wtrans<16, 32><<<(27 * 4 * 32 + 255) / 256, 256, 0, stream>>>(W0, Wt0);
    wtrans_h<32, 64><<<(27 * 4 * 64 + 255) / 256, 256, 0, stream>>>(W1, Wh1);
    wtrans_h<64, 128><<<(27 * 8 * 128 + 255) / 256, 256, 0, stream>>>(W2, Wh2);
    wtrans_h<128, 64><<<(27 * 16 * 64 + 255) / 256, 256, 0, stream>>>(W2t, Wh2t);
    wtrans_h<128, 64><<<(27 * 16 * 64 + 255) / 256, 256, 0, stream>>>(W1t, Wh1t);

    // block0: feats[N0,16] fp32 -> y0[N0,32] half
    sconv0<<<(N0 + 7) / 8, 256, 0, stream>>>(feats, Wt0, map0, N0, y0, zrow);
    bn_reduce_h<32><<<256, 256, 0, stream>>>(y0, N0, sums0);
    bn_apply_h<32><<<512, 256, 0, stream>>>(y0, N0, sums0, g0, b0);

    // block1: s1[N0,32] -> y1[N1,64]   (one wave per row)
    map_transpose<<<(N1 + 255) / 256, 256, 0, stream>>>(map1, N1, mapT);
    sconv_r1<32, 32, 64><<<(N1 + 3) / 4, 256, 0, stream>>>(
        y0, nullptr, Wh1, mapT, N1, y1);
    bn_reduce_h<64><<<256, 256, 0, stream>>>(y1, N1, sums1);
    bn_apply_h<64><<<512, 256, 0, stream>>>(y1, N1, sums1, g1, b1);

    // block2: s2[N1,64] -> y2[N2,128]
    map_transpose<<<(N2 + 255) / 256, 256, 0, stream>>>(map2, N2, mapT);
    sconv_r1<64, 64, 128><<<(N2 + 3) / 4, 256, 0, stream>>>(
        y1, nullptr, Wh2, mapT, N2, y2);
    bn_reduce_h<128><<<256, 256, 0, stream>>>(y2, N2, sums2);
    bn_apply_h<128><<<512, 256, 0, stream>>>(y2, N2, sums2, g2, b2);

    // block2_tr: s4[N2,128] -> y3[N1,64]
    map_transpose<<<(N1 + 255) / 256, 256, 0, stream>>>(map2t, N1, mapT);
    sconv_r1<128, 128, 64><<<(N1 + 3) / 4, 256, 0, stream>>>(
        y2, nullptr, Wh2t, mapT, N1, y3);
    bn_reduce_h<64><<<256, 256, 0, stream>>>(y3, N1, sums3);
    bn_apply_h<64><<<512, 256, 0, stream>>>(y3, N1, sums3, g2t, b2t);

    // block1_tr: concat(d2,s2)[N1,128] -> y4[N0,64]
    map_transpose<<<(N0 + 255) / 256, 256, 0, stream>>>(map1t, N0, mapT);
    sconv_r1<128, 64, 64><<<(N0 + 3) / 4, 256, 0, stream>>>(
        y3, y1, Wh1t, mapT, N0, y4);
    bn_reduce_h<64><<<256, 256, 0, stream>>>(y4, N0, sums4);
    bn_apply_h<64><<<512, 256, 0, stream>>>(y4, N0, sums4, g1t, b1t);

    // block0_tr: concat(d1,s1)[N0,96] -> out[N0,2] fp32
    sconv0t<<<(N0 + 7) / 8, 256, 0, stream>>>(y4, y0, W0t, map0t, N0,
                                              (float*)d_out, zrh);
}

// Round 13
// 1291.958 us; speedup vs baseline: 8.9024x; 1.0840x over previous
//
#include <hip/hip_runtime.h>
#include <cstddef>
#include <cstdint>

#define BN_EPS 1e-5f

typedef float f4 __attribute__((ext_vector_type(4)));
typedef _Float16 h2 __attribute__((ext_vector_type(2)));
typedef _Float16 h8 __attribute__((ext_vector_type(8)));

#if defined(__has_builtin)
#if __has_builtin(__builtin_amdgcn_fdot2)
#define DOT2(a, b, c) __builtin_amdgcn_fdot2((a), (b), (c), false)
#endif
#endif
#ifndef DOT2
#define DOT2(a, b, c) fmaf((float)(a)[1], (float)(b)[1], fmaf((float)(a)[0], (float)(b)[0], (c)))
#endif

// ---------------------------------------------------------------------------
// fp32 weight transpose (sconv0 only): W[27][CIN][COUT] -> Wt[k][ci/4][co][4]
// ---------------------------------------------------------------------------
template<int CIN, int COUT>
__global__ __launch_bounds__(256)
void wtrans(const float* __restrict__ W, float* __restrict__ Wt)
{
    const int t = blockIdx.x * 256 + threadIdx.x;
    constexpr int TOTAL = 27 * (CIN / 4) * COUT;
    if (t >= TOTAL) return;
    const int co = t % COUT;
    const int rest = t / COUT;
    const int c4 = rest % (CIN / 4);
    const int k  = rest / (CIN / 4);
    f4 v;
    #pragma unroll
    for (int u = 0; u < 4; ++u)
        v[u] = W[((size_t)k * CIN + c4 * 4 + u) * COUT + co];
    *(f4*)(Wt + (size_t)t * 4) = v;
}

// ---------------------------------------------------------------------------
// f16 weight transpose: W[27][CIN][COUT] -> Wh[k][ci/8][co][8]
// ---------------------------------------------------------------------------
template<int CIN, int COUT>
__global__ __launch_bounds__(256)
void wtrans_h(const float* __restrict__ W, _Float16* __restrict__ Wh)
{
    const int t = blockIdx.x * 256 + threadIdx.x;
    constexpr int TOTAL = 27 * (CIN / 8) * COUT;
    if (t >= TOTAL) return;
    const int co = t % COUT;
    const int rest = t / COUT;
    const int t8 = rest % (CIN / 8);
    const int k  = rest / (CIN / 8);
    h8 v;
    #pragma unroll
    for (int u = 0; u < 8; ++u)
        v[u] = (_Float16)W[((size_t)k * CIN + t8 * 8 + u) * COUT + co];
    *(h8*)(Wh + (size_t)t * 8) = v;
}

// ---------------------------------------------------------------------------
// Map transpose: map[27][Nout] -> mapT[Nout][32] (k-major per row, -1 pad).
// Used by the R=1 kernels only (sparse maps).
// ---------------------------------------------------------------------------
__global__ __launch_bounds__(256)
void map_transpose(const int* __restrict__ map, int Nout,
                   int* __restrict__ mapT)
{
    __shared__ int s[256][28];
    const int tid  = threadIdx.x;
    const int base = blockIdx.x * 256;
    const int j    = base + tid;
    for (int k = 0; k < 27; ++k)
        s[tid][k] = (j < Nout) ? map[(size_t)k * Nout + j] : -1;
    __syncthreads();
    for (int i = tid; i < 256 * 32; i += 256) {
        const int r = i >> 5, c = i & 31;
        if (base + r < Nout)
            mapT[(size_t)(base + r) * 32 + c] = (c < 27) ? s[r][c] : -1;
    }
}

// ---------------------------------------------------------------------------
// R=1 f16 sparse conv (SPARSE maps, ~1-1.5 valid k/row): one wave = one row.
// Minimizes slot waste; W amortization irrelevant at low density.
// ---------------------------------------------------------------------------
template<int CIN, int CINA, int COUT>
__global__ __launch_bounds__(256)
void sconv_r1(const _Float16* __restrict__ xA, const _Float16* __restrict__ xB,
              const _Float16* __restrict__ Wh, const int* __restrict__ mapT,
              int Nout, _Float16* __restrict__ out)
{
    constexpr int CINB = CIN - CINA;
    constexpr int CPL  = COUT / 64;
    constexpr int NT   = CIN / 8;
    const int lane = threadIdx.x & 63;
    const int j    = blockIdx.x * 4 + (threadIdx.x >> 6);

    int mk = -1;
    if (j < Nout && lane < 32) mk = mapT[(size_t)j * 32 + lane];
    unsigned long long act = __ballot(mk >= 0);   // bits 0..26 only

    float acc[CPL];
    #pragma unroll
    for (int c = 0; c < CPL; ++c) acc[c] = 0.f;

    while (act) {
        const int k = (int)__builtin_ctzll(act);
        act &= act - 1;
        const int m = __builtin_amdgcn_readlane(mk, k);   // uniform SGPR

        const _Float16* pA = xA + (size_t)m * CINA;
        const _Float16* pB = nullptr;
        if constexpr (CINB > 0) pB = xB + (size_t)m * CINB;

        const _Float16* Wk = Wh + (size_t)k * NT * COUT * 8;

        #pragma unroll
        for (int t = 0; t < NT; ++t) {
            const int ci = t * 8;
            h8 wv[CPL];
            #pragma unroll
            for (int c = 0; c < CPL; ++c)
                wv[c] = *(const h8*)(Wk + ((size_t)t * COUT + c * 64 + lane) * 8);
            const _Float16* p;
            if constexpr (CINB > 0)
                p = (ci < CINA) ? (pA + ci) : (pB + (ci - CINA));
            else
                p = pA + ci;
            const h8 xv = *(const h8*)p;
            const h2* xp = (const h2*)&xv;
            #pragma unroll
            for (int q = 0; q < 4; ++q) {
                #pragma unroll
                for (int c = 0; c < CPL; ++c) {
                    const h2* wp = (const h2*)&wv[c];
                    acc[c] = DOT2(xp[q], wp[q], acc[c]);
                }
            }
        }
    }

    if (j < Nout) {
        #pragma unroll
        for (int c = 0; c < CPL; ++c)
            out[(size_t)j * COUT + c * 64 + lane] = (_Float16)acc[c];
    }
}

// ---------------------------------------------------------------------------
// R=8 f16 sparse conv (DENSE maps, >=3 valid k/row): wave handles 8 rows.
// K_union/R amortizes the 16KB W k-slice over multiple valid rows -- the
// binding resource for dense convs is W L1 bandwidth (round-12 analysis:
// R=1 block2 re-read 7.9GB of W from L1 = ~200us of its 280us).
// Round-11-validated structure: ctz active-k loop, zrow-redirected uniform
// x pointers (unguarded batched s_loads), guarded dot2 blocks.
// ---------------------------------------------------------------------------
template<int CIN, int CINA, int COUT>
__global__ __launch_bounds__(256)
void sconv_big_h(const _Float16* __restrict__ xA, const _Float16* __restrict__ xB,
                 const _Float16* __restrict__ Wh, const int* __restrict__ map,
                 int Nout, _Float16* __restrict__ out,
                 const _Float16* __restrict__ zrh)
{
    constexpr int CINB = CIN - CINA;
    constexpr int CPL  = COUT / 64;
    constexpr int R    = 8;
    constexpr int NT   = CIN / 8;
    const int lane = threadIdx.x & 63;
    const int wave = threadIdx.x >> 6;
    const int row0 = (blockIdx.x * 4 + wave) * R;

    int mk[R];
    bool anyv = false;
    #pragma unroll
    for (int r = 0; r < R; ++r) {
        const int j = row0 + r;
        mk[r] = (lane < 27 && j < Nout) ? map[(size_t)lane * Nout + j] : -1;
        anyv |= (mk[r] >= 0);
    }
    unsigned long long act = __ballot(anyv);

    float acc[R][CPL];
    #pragma unroll
    for (int r = 0; r < R; ++r)
        #pragma unroll
        for (int c = 0; c < CPL; ++c) acc[r][c] = 0.f;

    while (act) {
        const int k = (int)__builtin_ctzll(act);
        act &= act - 1;

        int m[R];
        const _Float16* pA[R];
        const _Float16* pB[R];
        #pragma unroll
        for (int r = 0; r < R; ++r) {
            m[r] = __builtin_amdgcn_readlane(mk[r], k);   // uniform SGPR
            const bool v = (m[r] >= 0);
            pA[r] = v ? (xA + (size_t)m[r] * CINA) : zrh;  // uniform cselect
            if constexpr (CINB > 0)
                pB[r] = v ? (xB + (size_t)m[r] * CINB) : zrh;
        }

        const _Float16* Wk = Wh + (size_t)k * NT * COUT * 8;

        #pragma unroll
        for (int t = 0; t < NT; ++t) {
            const int ci = t * 8;
            h8 wv[CPL];
            #pragma unroll
            for (int c = 0; c < CPL; ++c)
                wv[c] = *(const h8*)(Wk + ((size_t)t * COUT + c * 64 + lane) * 8);

            h8 xv[R];
            #pragma unroll
            for (int r = 0; r < R; ++r) {
                const _Float16* p;
                if constexpr (CINB > 0)
                    p = (ci < CINA) ? (pA[r] + ci) : (pB[r] + (ci - CINA));
                else
                    p = pA[r] + ci;
                xv[r] = *(const h8*)p;
            }

            #pragma unroll
            for (int r = 0; r < R; ++r) {
                if (m[r] >= 0) {
                    const h2* xp = (const h2*)&xv[r];
                    #pragma unroll
                    for (int q = 0; q < 4; ++q) {
                        #pragma unroll
                        for (int c = 0; c < CPL; ++c) {
                            const h2* wp = (const h2*)&wv[c];
                            acc[r][c] = DOT2(xp[q], wp[q], acc[r][c]);
                        }
                    }
                }
            }
        }
    }

    #pragma unroll
    for (int r = 0; r < R; ++r) {
        const int j = row0 + r;
        if (j < Nout) {
            #pragma unroll
            for (int c = 0; c < CPL; ++c)
                out[(size_t)j * COUT + c * 64 + lane] = (_Float16)acc[r][c];
        }
    }
}

// ---------------------------------------------------------------------------
// conv0: CIN=16 (fp32 input feats), COUT=32 -> half output.
// ---------------------------------------------------------------------------
__global__ __launch_bounds__(256)
void sconv0(const float* __restrict__ x, const float* __restrict__ Wt,
            const int* __restrict__ map, int N, _Float16* __restrict__ out,
            const float* __restrict__ zrow)
{
    const int tid  = threadIdx.x;
    const int lane = tid & 63;
    const int l32  = tid & 31;
    const int co   = l32;
    const int j    = blockIdx.x * 8 + (tid >> 5);

    int mk = (l32 < 27 && j < N) ? map[(size_t)l32 * N + j] : -1;

    float a0 = 0.f, a1 = 0.f, a2 = 0.f, a3 = 0.f;
    for (int k = 0; k < 27; ++k) {
        const int m = __shfl(mk, (lane & 32) + k);
        if (__ballot(m >= 0) == 0ull) continue;
        const float* xr = (m >= 0) ? (x + (size_t)m * 16) : zrow;
        const float* wk = Wt + (size_t)k * 16 * 32;
        f4 w0 = *(const f4*)(wk + (0 * 32 + co) * 4);
        f4 w1 = *(const f4*)(wk + (1 * 32 + co) * 4);
        f4 w2 = *(const f4*)(wk + (2 * 32 + co) * 4);
        f4 w3 = *(const f4*)(wk + (3 * 32 + co) * 4);
        f4 x0 = *(const f4*)(xr);
        f4 x1 = *(const f4*)(xr + 4);
        f4 x2 = *(const f4*)(xr + 8);
        f4 x3 = *(const f4*)(xr + 12);
        #pragma unroll
        for (int u = 0; u < 4; ++u) {
            a0 = fmaf(x0[u], w0[u], a0);
            a1 = fmaf(x1[u], w1[u], a1);
            a2 = fmaf(x2[u], w2[u], a2);
            a3 = fmaf(x3[u], w3[u], a3);
        }
    }
    if (j < N) out[(size_t)j * 32 + co] = (_Float16)((a0 + a1) + (a2 + a3));
}

// ---------------------------------------------------------------------------
// conv0t: x = concat(d1[*,64] half, s1[*,32] half), COUT=2, fp32 W & output.
// ---------------------------------------------------------------------------
__global__ __launch_bounds__(256)
void sconv0t(const _Float16* __restrict__ d1, const _Float16* __restrict__ s1,
             const float* __restrict__ W /*[27,96,2]*/,
             const int* __restrict__ map, int N, float* __restrict__ out,
             const _Float16* __restrict__ zrh)
{
    const int tid  = threadIdx.x;
    const int lane = tid & 63;
    const int l32  = tid & 31;
    const int j    = blockIdx.x * 8 + (tid >> 5);

    int mk = (l32 < 27 && j < N) ? map[(size_t)l32 * N + j] : -1;

    float a0 = 0.f, a1 = 0.f;
    for (int k = 0; k < 27; ++k) {
        const int m = __shfl(mk, (lane & 32) + k);
        if (__ballot(m >= 0) == 0ull) continue;
        const _Float16* p1 = (m >= 0) ? (d1 + (size_t)m * 64) : zrh;
        const _Float16* p2 = (m >= 0) ? (s1 + (size_t)m * 32) : zrh;
        const float* w = W + (size_t)k * 96 * 2;
        const float x0 = (float)p1[l32];
        const float x1 = (float)p1[l32 + 32];
        const float x2 = (float)p2[l32];
        a0 = fmaf(x0, w[l32 * 2 + 0], a0);
        a1 = fmaf(x0, w[l32 * 2 + 1], a1);
        a0 = fmaf(x1, w[(l32 + 32) * 2 + 0], a0);
        a1 = fmaf(x1, w[(l32 + 32) * 2 + 1], a1);
        a0 = fmaf(x2, w[(l32 + 64) * 2 + 0], a0);
        a1 = fmaf(x2, w[(l32 + 64) * 2 + 1], a1);
    }
    #pragma unroll
    for (int off = 1; off < 32; off <<= 1) {
        a0 += __shfl_xor(a0, off, 32);
        a1 += __shfl_xor(a1, off, 32);
    }
    if (l32 == 0 && j < N) {
        out[(size_t)j * 2 + 0] = a0;
        out[(size_t)j * 2 + 1] = a1;
    }
}

// ---------------------------------------------------------------------------
// BN pass 1 on half tensors
// ---------------------------------------------------------------------------
template<int C>
__global__ __launch_bounds__(256)
void bn_reduce_h(const _Float16* __restrict__ x, int N,
                 float* __restrict__ sums)
{
    constexpr int RG = 256 / C;
    const int tid = threadIdx.x;
    const int c   = tid % C;
    const int rg  = tid / C;
    float s = 0.f, s2 = 0.f;
    for (int j = blockIdx.x * RG + rg; j < N; j += gridDim.x * RG) {
        const float v = (float)x[(size_t)j * C + c];
        s += v;
        s2 += v * v;
    }
    __shared__ float sh[2 * 256];
    sh[tid] = s;
    sh[256 + tid] = s2;
    __syncthreads();
    for (int stride = 128; stride >= C; stride >>= 1) {
        if (tid < stride) {
            sh[tid] += sh[tid + stride];
            sh[256 + tid] += sh[256 + tid + stride];
        }
        __syncthreads();
    }
    if (tid < C) {
        atomicAdd(&sums[c], sh[tid]);
        atomicAdd(&sums[C + c], sh[256 + tid]);
    }
}

// ---------------------------------------------------------------------------
// BN pass 2 on half tensors
// ---------------------------------------------------------------------------
template<int C>
__global__ __launch_bounds__(256)
void bn_apply_h(_Float16* __restrict__ x, int N,
                const float* __restrict__ sums,
                const float* __restrict__ g, const float* __restrict__ b)
{
    const int tid = blockIdx.x * blockDim.x + threadIdx.x;
    const int c = tid % C;
    const float invN = 1.0f / (float)N;
    const float mean = sums[c] * invN;
    float var = sums[C + c] * invN - mean * mean;
    var = fmaxf(var, 0.f);
    const float sc = g[c] * rsqrtf(var + BN_EPS);
    const float sh = b[c] - mean * sc;
    const int rows_stride = (gridDim.x * blockDim.x) / C;
    for (int j = tid / C; j < N; j += rows_stride) {
        const size_t i = (size_t)j * C + c;
        const float v = fmaf((float)x[i], sc, sh);
        x[i] = (_Float16)(v > 0.f ? v : 0.f);
    }
}

// ---------------------------------------------------------------------------
extern "C" void kernel_launch(void* const* d_in, const int* in_sizes, int n_in,
                              void* d_out, int out_size, void* d_ws, size_t ws_size,
                              hipStream_t stream)
{
    const float* feats = (const float*)d_in[0];
    const float* W0  = (const float*)d_in[1];
    const float* g0  = (const float*)d_in[2];
    const float* b0  = (const float*)d_in[3];
    const float* W1  = (const float*)d_in[4];
    const float* g1  = (const float*)d_in[5];
    const float* b1  = (const float*)d_in[6];
    const float* W2  = (const float*)d_in[7];
    const float* g2  = (const float*)d_in[8];
    const float* b2  = (const float*)d_in[9];
    const float* W2t = (const float*)d_in[10];
    const float* g2t = (const float*)d_in[11];
    const float* b2t = (const float*)d_in[12];
    const float* W1t = (const float*)d_in[13];
    const float* g1t = (const float*)d_in[14];
    const float* b1t = (const float*)d_in[15];
    const float* W0t = (const float*)d_in[16];
    const int* map0  = (const int*)d_in[17];
    const int* map1  = (const int*)d_in[18];
    const int* map2  = (const int*)d_in[19];
    const int* map2t = (const int*)d_in[20];
    const int* map1t = (const int*)d_in[21];
    const int* map0t = (const int*)d_in[22];

    const int N0 = in_sizes[0] / 16;
    const int N1 = in_sizes[18] / 27;
    const int N2 = in_sizes[19] / 27;

    float* ws = (float*)d_ws;
    float* sums  = ws;          // 704 floats of BN accumulators
    float* sums0 = sums;        // 2*32
    float* sums1 = sums + 64;   // 2*64
    float* sums2 = sums + 192;  // 2*128
    float* sums3 = sums + 448;  // 2*64
    float* sums4 = sums + 576;  // 2*64
    float* zrow  = sums + 704;  // 128 zeroed floats (fp32 & f16 zero rows)
    float* Wt0   = zrow + 128;  // 27*16*32 fp32
    _Float16* hb = (_Float16*)(Wt0 + 27 * 16 * 32);
    _Float16* Wh1  = hb;                        // 27*32*64
    _Float16* Wh2  = Wh1 + 27 * 32 * 64;        // 27*64*128
    _Float16* Wh2t = Wh2 + 27 * 64 * 128;       // 27*128*64
    _Float16* Wh1t = Wh2t + 27 * 128 * 64;      // 27*128*64
    _Float16* y0 = Wh1t + 27 * 128 * 64;        // [N0,32]  s1
    _Float16* y1 = y0 + (size_t)N0 * 32;        // [N1,64]  s2
    _Float16* y2 = y1 + (size_t)N1 * 64;        // [N2,128] s4
    _Float16* y3 = y2 + (size_t)N2 * 128;       // [N1,64]  d2
    _Float16* y4 = y3 + (size_t)N1 * 64;        // [N0,64]  d1
    int* mapT = (int*)(y4 + (size_t)N0 * 64);   // [Nmax,32] transposed map
    const _Float16* zrh = (const _Float16*)zrow;

    (void)hipMemsetAsync(sums, 0, (704 + 128) * sizeof(float), stream);

    // weight transposes (tiny)
    wtrans<16, 32><<<(27 * 4 * 32 + 255) / 256, 256, 0, stream>>>(W0, Wt0);
    wtrans_h<32, 64><<<(27 * 4 * 64 + 255) / 256, 256, 0, stream>>>(W1, Wh1);
    wtrans_h<64, 128><<<(27 * 8 * 128 + 255) / 256, 256, 0, stream>>>(W2, Wh2);
    wtrans_h<128, 64><<<(27 * 16 * 64 + 255) / 256, 256, 0, stream>>>(W2t, Wh2t);
    wtrans_h<128, 64><<<(27 * 16 * 64 + 255) / 256, 256, 0, stream>>>(W1t, Wh1t);

    // block0: feats[N0,16] fp32 -> y0[N0,32] half
    sconv0<<<(N0 + 7) / 8, 256, 0, stream>>>(feats, Wt0, map0, N0, y0, zrow);
    bn_reduce_h<32><<<256, 256, 0, stream>>>(y0, N0, sums0);
    bn_apply_h<32><<<512, 256, 0, stream>>>(y0, N0, sums0, g0, b0);

    // block1 (SPARSE map ~5%): one wave per row
    map_transpose<<<(N1 + 255) / 256, 256, 0, stream>>>(map1, N1, mapT);
    sconv_r1<32, 32, 64><<<(N1 + 3) / 4, 256, 0, stream>>>(
        y0, nullptr, Wh1, mapT, N1, y1);
    bn_reduce_h<64><<<256, 256, 0, stream>>>(y1, N1, sums1);
    bn_apply_h<64><<<512, 256, 0, stream>>>(y1, N1, sums1, g1, b1);

    // block2 (DENSE map ~30%): R=8 rows/wave amortizes W k-slices
    sconv_big_h<64, 64, 128><<<(N2 + 31) / 32, 256, 0, stream>>>(
        y1, nullptr, Wh2, map2, N2, y2, zrh);
    bn_reduce_h<128><<<256, 256, 0, stream>>>(y2, N2, sums2);
    bn_apply_h<128><<<512, 256, 0, stream>>>(y2, N2, sums2, g2, b2);

    // block2_tr (DENSE map ~12%): R=8 rows/wave
    sconv_big_h<128, 128, 64><<<(N1 + 31) / 32, 256, 0, stream>>>(
        y2, nullptr, Wh2t, map2t, N1, y3, zrh);
    bn_reduce_h<64><<<256, 256, 0, stream>>>(y3, N1, sums3);
    bn_apply_h<64><<<512, 256, 0, stream>>>(y3, N1, sums3, g2t, b2t);

    // block1_tr (SPARSE map ~4%): one wave per row
    map_transpose<<<(N0 + 255) / 256, 256, 0, stream>>>(map1t, N0, mapT);
    sconv_r1<128, 64, 64><<<(N0 + 3) / 4, 256, 0, stream>>>(
        y3, y1, Wh1t, mapT, N0, y4);
    bn_reduce_h<64><<<256, 256, 0, stream>>>(y4, N0, sums4);
    bn_apply_h<64><<<512, 256, 0, stream>>>(y4, N0, sums4, g1t, b1t);

    // block0_tr: concat(d1,s1)[N0,96] -> out[N0,2] fp32
    sconv0t<<<(N0 + 7) / 8, 256, 0, stream>>>(y4, y0, W0t, map0t, N0,
                                              (float*)d_out, zrh);
}

// Round 14
// 1232.404 us; speedup vs baseline: 9.3326x; 1.0483x over previous
//
#include <hip/hip_runtime.h>
#include <cstddef>
#include <cstdint>

#define BN_EPS 1e-5f

typedef float f4 __attribute__((ext_vector_type(4)));
typedef _Float16 h2 __attribute__((ext_vector_type(2)));
typedef _Float16 h8 __attribute__((ext_vector_type(8)));

#if defined(__has_builtin)
#if __has_builtin(__builtin_amdgcn_fdot2)
#define DOT2(a, b, c) __builtin_amdgcn_fdot2((a), (b), (c), false)
#endif
#endif
#ifndef DOT2
#define DOT2(a, b, c) fmaf((float)(a)[1], (float)(b)[1], fmaf((float)(a)[0], (float)(b)[0], (c)))
#endif

// ---------------------------------------------------------------------------
// fp32 weight transpose (sconv0 only): W[27][CIN][COUT] -> Wt[k][ci/4][co][4]
// ---------------------------------------------------------------------------
template<int CIN, int COUT>
__global__ __launch_bounds__(256)
void wtrans(const float* __restrict__ W, float* __restrict__ Wt)
{
    const int t = blockIdx.x * 256 + threadIdx.x;
    constexpr int TOTAL = 27 * (CIN / 4) * COUT;
    if (t >= TOTAL) return;
    const int co = t % COUT;
    const int rest = t / COUT;
    const int c4 = rest % (CIN / 4);
    const int k  = rest / (CIN / 4);
    f4 v;
    #pragma unroll
    for (int u = 0; u < 4; ++u)
        v[u] = W[((size_t)k * CIN + c4 * 4 + u) * COUT + co];
    *(f4*)(Wt + (size_t)t * 4) = v;
}

// ---------------------------------------------------------------------------
// f16 weight transpose: W[27][CIN][COUT] -> Wh[k][ci/8][co][8]
// ---------------------------------------------------------------------------
template<int CIN, int COUT>
__global__ __launch_bounds__(256)
void wtrans_h(const float* __restrict__ W, _Float16* __restrict__ Wh)
{
    const int t = blockIdx.x * 256 + threadIdx.x;
    constexpr int TOTAL = 27 * (CIN / 8) * COUT;
    if (t >= TOTAL) return;
    const int co = t % COUT;
    const int rest = t / COUT;
    const int t8 = rest % (CIN / 8);
    const int k  = rest / (CIN / 8);
    h8 v;
    #pragma unroll
    for (int u = 0; u < 8; ++u)
        v[u] = (_Float16)W[((size_t)k * CIN + t8 * 8 + u) * COUT + co];
    *(h8*)(Wh + (size_t)t * 8) = v;
}

// ---------------------------------------------------------------------------
// Map transpose: map[27][Nout] -> mapT[Nout][32] (k-major per row, -1 pad).
// ---------------------------------------------------------------------------
__global__ __launch_bounds__(256)
void map_transpose(const int* __restrict__ map, int Nout,
                   int* __restrict__ mapT)
{
    __shared__ int s[256][28];
    const int tid  = threadIdx.x;
    const int base = blockIdx.x * 256;
    const int j    = base + tid;
    for (int k = 0; k < 27; ++k)
        s[tid][k] = (j < Nout) ? map[(size_t)k * Nout + j] : -1;
    __syncthreads();
    for (int i = tid; i < 256 * 32; i += 256) {
        const int r = i >> 5, c = i & 31;
        if (base + r < Nout)
            mapT[(size_t)(base + r) * 32 + c] = (c < 27) ? s[r][c] : -1;
    }
}

// ---------------------------------------------------------------------------
// R=1 f16 sparse conv (SPARSE maps): one wave = one row.
// ---------------------------------------------------------------------------
template<int CIN, int CINA, int COUT>
__global__ __launch_bounds__(256)
void sconv_r1(const _Float16* __restrict__ xA, const _Float16* __restrict__ xB,
              const _Float16* __restrict__ Wh, const int* __restrict__ mapT,
              int Nout, _Float16* __restrict__ out)
{
    constexpr int CINB = CIN - CINA;
    constexpr int CPL  = COUT / 64;
    constexpr int NT   = CIN / 8;
    const int lane = threadIdx.x & 63;
    const int j    = blockIdx.x * 4 + (threadIdx.x >> 6);

    int mk = -1;
    if (j < Nout && lane < 32) mk = mapT[(size_t)j * 32 + lane];
    unsigned long long act = __ballot(mk >= 0);   // bits 0..26 only

    float acc[CPL];
    #pragma unroll
    for (int c = 0; c < CPL; ++c) acc[c] = 0.f;

    while (act) {
        const int k = (int)__builtin_ctzll(act);
        act &= act - 1;
        const int m = __builtin_amdgcn_readlane(mk, k);   // uniform SGPR

        const _Float16* pA = xA + (size_t)m * CINA;
        const _Float16* pB = nullptr;
        if constexpr (CINB > 0) pB = xB + (size_t)m * CINB;

        const _Float16* Wk = Wh + (size_t)k * NT * COUT * 8;

        #pragma unroll
        for (int t = 0; t < NT; ++t) {
            const int ci = t * 8;
            h8 wv[CPL];
            #pragma unroll
            for (int c = 0; c < CPL; ++c)
                wv[c] = *(const h8*)(Wk + ((size_t)t * COUT + c * 64 + lane) * 8);
            const _Float16* p;
            if constexpr (CINB > 0)
                p = (ci < CINA) ? (pA + ci) : (pB + (ci - CINA));
            else
                p = pA + ci;
            const h8 xv = *(const h8*)p;
            const h2* xp = (const h2*)&xv;
            #pragma unroll
            for (int q = 0; q < 4; ++q) {
                #pragma unroll
                for (int c = 0; c < CPL; ++c) {
                    const h2* wp = (const h2*)&wv[c];
                    acc[c] = DOT2(xp[q], wp[q], acc[c]);
                }
            }
        }
    }

    if (j < Nout) {
        #pragma unroll
        for (int c = 0; c < CPL; ++c)
            out[(size_t)j * COUT + c * 64 + lane] = (_Float16)acc[c];
    }
}

// ---------------------------------------------------------------------------
// R-rows/wave f16 sparse conv (DENSE/MID maps). R is now a tunable template
// param: R=8 for ~30% density (W amortization), R=4 for ~12% (balance
// between W-slices/row = K_union/R and slot-loads/row = K_union).
// ---------------------------------------------------------------------------
template<int CIN, int CINA, int COUT, int R>
__global__ __launch_bounds__(256)
void sconv_big_h(const _Float16* __restrict__ xA, const _Float16* __restrict__ xB,
                 const _Float16* __restrict__ Wh, const int* __restrict__ map,
                 int Nout, _Float16* __restrict__ out,
                 const _Float16* __restrict__ zrh)
{
    constexpr int CINB = CIN - CINA;
    constexpr int CPL  = COUT / 64;
    constexpr int NT   = CIN / 8;
    const int lane = threadIdx.x & 63;
    const int wave = threadIdx.x >> 6;
    const int row0 = (blockIdx.x * 4 + wave) * R;

    int mk[R];
    bool anyv = false;
    #pragma unroll
    for (int r = 0; r < R; ++r) {
        const int j = row0 + r;
        mk[r] = (lane < 27 && j < Nout) ? map[(size_t)lane * Nout + j] : -1;
        anyv |= (mk[r] >= 0);
    }
    unsigned long long act = __ballot(anyv);

    float acc[R][CPL];
    #pragma unroll
    for (int r = 0; r < R; ++r)
        #pragma unroll
        for (int c = 0; c < CPL; ++c) acc[r][c] = 0.f;

    while (act) {
        const int k = (int)__builtin_ctzll(act);
        act &= act - 1;

        int m[R];
        const _Float16* pA[R];
        const _Float16* pB[R];
        #pragma unroll
        for (int r = 0; r < R; ++r) {
            m[r] = __builtin_amdgcn_readlane(mk[r], k);   // uniform SGPR
            const bool v = (m[r] >= 0);
            pA[r] = v ? (xA + (size_t)m[r] * CINA) : zrh;  // uniform cselect
            if constexpr (CINB > 0)
                pB[r] = v ? (xB + (size_t)m[r] * CINB) : zrh;
        }

        const _Float16* Wk = Wh + (size_t)k * NT * COUT * 8;

        #pragma unroll
        for (int t = 0; t < NT; ++t) {
            const int ci = t * 8;
            h8 wv[CPL];
            #pragma unroll
            for (int c = 0; c < CPL; ++c)
                wv[c] = *(const h8*)(Wk + ((size_t)t * COUT + c * 64 + lane) * 8);

            h8 xv[R];
            #pragma unroll
            for (int r = 0; r < R; ++r) {
                const _Float16* p;
                if constexpr (CINB > 0)
                    p = (ci < CINA) ? (pA[r] + ci) : (pB[r] + (ci - CINA));
                else
                    p = pA[r] + ci;
                xv[r] = *(const h8*)p;
            }

            #pragma unroll
            for (int r = 0; r < R; ++r) {
                if (m[r] >= 0) {
                    const h2* xp = (const h2*)&xv[r];
                    #pragma unroll
                    for (int q = 0; q < 4; ++q) {
                        #pragma unroll
                        for (int c = 0; c < CPL; ++c) {
                            const h2* wp = (const h2*)&wv[c];
                            acc[r][c] = DOT2(xp[q], wp[q], acc[r][c]);
                        }
                    }
                }
            }
        }
    }

    #pragma unroll
    for (int r = 0; r < R; ++r) {
        const int j = row0 + r;
        if (j < Nout) {
            #pragma unroll
            for (int c = 0; c < CPL; ++c)
                out[(size_t)j * COUT + c * 64 + lane] = (_Float16)acc[r][c];
        }
    }
}

// ---------------------------------------------------------------------------
// conv0: CIN=16 (fp32 feats), COUT=32 -> half out. 2 rows/wave (32 lanes
// each). Round-14: ctz loop over the UNION of the two rows' active-k masks
// (removes ~22 dead iterations of shfl+ballot+branch per wave at ~83%
// dead-k rate).
// ---------------------------------------------------------------------------
__global__ __launch_bounds__(256)
void sconv0(const float* __restrict__ x, const float* __restrict__ Wt,
            const int* __restrict__ map, int N, _Float16* __restrict__ out,
            const float* __restrict__ zrow)
{
    const int tid  = threadIdx.x;
    const int lane = tid & 63;
    const int l32  = tid & 31;
    const int co   = l32;
    const int j    = blockIdx.x * 8 + (tid >> 5);

    int mk = (l32 < 27 && j < N) ? map[(size_t)l32 * N + j] : -1;
    const unsigned long long bal = __ballot(mk >= 0);
    unsigned int act = (unsigned int)((bal | (bal >> 32)) & 0x7FFFFFFu);

    float a0 = 0.f, a1 = 0.f, a2 = 0.f, a3 = 0.f;
    while (act) {
        const int k = (int)__builtin_ctz(act);
        act &= act - 1;
        const int m = __shfl(mk, (lane & 32) + k);
        const float* xr = (m >= 0) ? (x + (size_t)m * 16) : zrow;
        const float* wk = Wt + (size_t)k * 16 * 32;
        f4 w0 = *(const f4*)(wk + (0 * 32 + co) * 4);
        f4 w1 = *(const f4*)(wk + (1 * 32 + co) * 4);
        f4 w2 = *(const f4*)(wk + (2 * 32 + co) * 4);
        f4 w3 = *(const f4*)(wk + (3 * 32 + co) * 4);
        f4 x0 = *(const f4*)(xr);
        f4 x1 = *(const f4*)(xr + 4);
        f4 x2 = *(const f4*)(xr + 8);
        f4 x3 = *(const f4*)(xr + 12);
        #pragma unroll
        for (int u = 0; u < 4; ++u) {
            a0 = fmaf(x0[u], w0[u], a0);
            a1 = fmaf(x1[u], w1[u], a1);
            a2 = fmaf(x2[u], w2[u], a2);
            a3 = fmaf(x3[u], w3[u], a3);
        }
    }
    if (j < N) out[(size_t)j * 32 + co] = (_Float16)((a0 + a1) + (a2 + a3));
}

// ---------------------------------------------------------------------------
// conv0t: concat(d1[*,64]h, s1[*,32]h) -> out[N0,2] fp32. 2 rows/wave,
// ctz-union loop as in sconv0.
// ---------------------------------------------------------------------------
__global__ __launch_bounds__(256)
void sconv0t(const _Float16* __restrict__ d1, const _Float16* __restrict__ s1,
             const float* __restrict__ W /*[27,96,2]*/,
             const int* __restrict__ map, int N, float* __restrict__ out,
             const _Float16* __restrict__ zrh)
{
    const int tid  = threadIdx.x;
    const int lane = tid & 63;
    const int l32  = tid & 31;
    const int j    = blockIdx.x * 8 + (tid >> 5);

    int mk = (l32 < 27 && j < N) ? map[(size_t)l32 * N + j] : -1;
    const unsigned long long bal = __ballot(mk >= 0);
    unsigned int act = (unsigned int)((bal | (bal >> 32)) & 0x7FFFFFFu);

    float a0 = 0.f, a1 = 0.f;
    while (act) {
        const int k = (int)__builtin_ctz(act);
        act &= act - 1;
        const int m = __shfl(mk, (lane & 32) + k);
        const _Float16* p1 = (m >= 0) ? (d1 + (size_t)m * 64) : zrh;
        const _Float16* p2 = (m >= 0) ? (s1 + (size_t)m * 32) : zrh;
        const float* w = W + (size_t)k * 96 * 2;
        const float x0 = (float)p1[l32];
        const float x1 = (float)p1[l32 + 32];
        const float x2 = (float)p2[l32];
        a0 = fmaf(x0, w[l32 * 2 + 0], a0);
        a1 = fmaf(x0, w[l32 * 2 + 1], a1);
        a0 = fmaf(x1, w[(l32 + 32) * 2 + 0], a0);
        a1 = fmaf(x1, w[(l32 + 32) * 2 + 1], a1);
        a0 = fmaf(x2, w[(l32 + 64) * 2 + 0], a0);
        a1 = fmaf(x2, w[(l32 + 64) * 2 + 1], a1);
    }
    #pragma unroll
    for (int off = 1; off < 32; off <<= 1) {
        a0 += __shfl_xor(a0, off, 32);
        a1 += __shfl_xor(a1, off, 32);
    }
    if (l32 == 0 && j < N) {
        out[(size_t)j * 2 + 0] = a0;
        out[(size_t)j * 2 + 1] = a1;
    }
}

// ---------------------------------------------------------------------------
// BN pass 1 on half tensors
// ---------------------------------------------------------------------------
template<int C>
__global__ __launch_bounds__(256)
void bn_reduce_h(const _Float16* __restrict__ x, int N,
                 float* __restrict__ sums)
{
    constexpr int RG = 256 / C;
    const int tid = threadIdx.x;
    const int c   = tid % C;
    const int rg  = tid / C;
    float s = 0.f, s2 = 0.f;
    for (int j = blockIdx.x * RG + rg; j < N; j += gridDim.x * RG) {
        const float v = (float)x[(size_t)j * C + c];
        s += v;
        s2 += v * v;
    }
    __shared__ float sh[2 * 256];
    sh[tid] = s;
    sh[256 + tid] = s2;
    __syncthreads();
    for (int stride = 128; stride >= C; stride >>= 1) {
        if (tid < stride) {
            sh[tid] += sh[tid + stride];
            sh[256 + tid] += sh[256 + tid + stride];
        }
        __syncthreads();
    }
    if (tid < C) {
        atomicAdd(&sums[c], sh[tid]);
        atomicAdd(&sums[C + c], sh[256 + tid]);
    }
}

// ---------------------------------------------------------------------------
// BN pass 2 on half tensors
// ---------------------------------------------------------------------------
template<int C>
__global__ __launch_bounds__(256)
void bn_apply_h(_Float16* __restrict__ x, int N,
                const float* __restrict__ sums,
                const float* __restrict__ g, const float* __restrict__ b)
{
    const int tid = blockIdx.x * blockDim.x + threadIdx.x;
    const int c = tid % C;
    const float invN = 1.0f / (float)N;
    const float mean = sums[c] * invN;
    float var = sums[C + c] * invN - mean * mean;
    var = fmaxf(var, 0.f);
    const float sc = g[c] * rsqrtf(var + BN_EPS);
    const float sh = b[c] - mean * sc;
    const int rows_stride = (gridDim.x * blockDim.x) / C;
    for (int j = tid / C; j < N; j += rows_stride) {
        const size_t i = (size_t)j * C + c;
        const float v = fmaf((float)x[i], sc, sh);
        x[i] = (_Float16)(v > 0.f ? v : 0.f);
    }
}

// ---------------------------------------------------------------------------
extern "C" void kernel_launch(void* const* d_in, const int* in_sizes, int n_in,
                              void* d_out, int out_size, void* d_ws, size_t ws_size,
                              hipStream_t stream)
{
    const float* feats = (const float*)d_in[0];
    const float* W0  = (const float*)d_in[1];
    const float* g0  = (const float*)d_in[2];
    const float* b0  = (const float*)d_in[3];
    const float* W1  = (const float*)d_in[4];
    const float* g1  = (const float*)d_in[5];
    const float* b1  = (const float*)d_in[6];
    const float* W2  = (const float*)d_in[7];
    const float* g2  = (const float*)d_in[8];
    const float* b2  = (const float*)d_in[9];
    const float* W2t = (const float*)d_in[10];
    const float* g2t = (const float*)d_in[11];
    const float* b2t = (const float*)d_in[12];
    const float* W1t = (const float*)d_in[13];
    const float* g1t = (const float*)d_in[14];
    const float* b1t = (const float*)d_in[15];
    const float* W0t = (const float*)d_in[16];
    const int* map0  = (const int*)d_in[17];
    const int* map1  = (const int*)d_in[18];
    const int* map2  = (const int*)d_in[19];
    const int* map2t = (const int*)d_in[20];
    const int* map1t = (const int*)d_in[21];
    const int* map0t = (const int*)d_in[22];

    const int N0 = in_sizes[0] / 16;
    const int N1 = in_sizes[18] / 27;
    const int N2 = in_sizes[19] / 27;

    float* ws = (float*)d_ws;
    float* sums  = ws;          // 704 floats of BN accumulators
    float* sums0 = sums;        // 2*32
    float* sums1 = sums + 64;   // 2*64
    float* sums2 = sums + 192;  // 2*128
    float* sums3 = sums + 448;  // 2*64
    float* sums4 = sums + 576;  // 2*64
    float* zrow  = sums + 704;  // 128 zeroed floats (fp32 & f16 zero rows)
    float* Wt0   = zrow + 128;  // 27*16*32 fp32
    _Float16* hb = (_Float16*)(Wt0 + 27 * 16 * 32);
    _Float16* Wh1  = hb;                        // 27*32*64
    _Float16* Wh2  = Wh1 + 27 * 32 * 64;        // 27*64*128
    _Float16* Wh2t = Wh2 + 27 * 64 * 128;       // 27*128*64
    _Float16* Wh1t = Wh2t + 27 * 128 * 64;      // 27*128*64
    _Float16* y0 = Wh1t + 27 * 128 * 64;        // [N0,32]  s1
    _Float16* y1 = y0 + (size_t)N0 * 32;        // [N1,64]  s2
    _Float16* y2 = y1 + (size_t)N1 * 64;        // [N2,128] s4
    _Float16* y3 = y2 + (size_t)N2 * 128;       // [N1,64]  d2
    _Float16* y4 = y3 + (size_t)N1 * 64;        // [N0,64]  d1
    int* mapT = (int*)(y4 + (size_t)N0 * 64);   // [Nmax,32] transposed map
    const _Float16* zrh = (const _Float16*)zrow;

    (void)hipMemsetAsync(sums, 0, (704 + 128) * sizeof(float), stream);

    // weight transposes (tiny)
    wtrans<16, 32><<<(27 * 4 * 32 + 255) / 256, 256, 0, stream>>>(W0, Wt0);
    wtrans_h<32, 64><<<(27 * 4 * 64 + 255) / 256, 256, 0, stream>>>(W1, Wh1);
    wtrans_h<64, 128><<<(27 * 8 * 128 + 255) / 256, 256, 0, stream>>>(W2, Wh2);
    wtrans_h<128, 64><<<(27 * 16 * 64 + 255) / 256, 256, 0, stream>>>(W2t, Wh2t);
    wtrans_h<128, 64><<<(27 * 16 * 64 + 255) / 256, 256, 0, stream>>>(W1t, Wh1t);

    // block0: feats[N0,16] fp32 -> y0[N0,32] half
    sconv0<<<(N0 + 7) / 8, 256, 0, stream>>>(feats, Wt0, map0, N0, y0, zrow);
    bn_reduce_h<32><<<256, 256, 0, stream>>>(y0, N0, sums0);
    bn_apply_h<32><<<512, 256, 0, stream>>>(y0, N0, sums0, g0, b0);

    // block1 (SPARSE map): one wave per row
    map_transpose<<<(N1 + 255) / 256, 256, 0, stream>>>(map1, N1, mapT);
    sconv_r1<32, 32, 64><<<(N1 + 3) / 4, 256, 0, stream>>>(
        y0, nullptr, Wh1, mapT, N1, y1);
    bn_reduce_h<64><<<256, 256, 0, stream>>>(y1, N1, sums1);
    bn_apply_h<64><<<512, 256, 0, stream>>>(y1, N1, sums1, g1, b1);

    // block2 (DENSE map ~30%): R=8 rows/wave
    sconv_big_h<64, 64, 128, 8><<<(N2 + 31) / 32, 256, 0, stream>>>(
        y1, nullptr, Wh2, map2, N2, y2, zrh);
    bn_reduce_h<128><<<256, 256, 0, stream>>>(y2, N2, sums2);
    bn_apply_h<128><<<512, 256, 0, stream>>>(y2, N2, sums2, g2, b2);

    // block2_tr (MID map ~12.5%): R=4 rows/wave (round-14 probe)
    sconv_big_h<128, 128, 64, 4><<<(N1 + 15) / 16, 256, 0, stream>>>(
        y2, nullptr, Wh2t, map2t, N1, y3, zrh);
    bn_reduce_h<64><<<256, 256, 0, stream>>>(y3, N1, sums3);
    bn_apply_h<64><<<512, 256, 0, stream>>>(y3, N1, sums3, g2t, b2t);

    // block1_tr (SPARSE map): one wave per row
    map_transpose<<<(N0 + 255) / 256, 256, 0, stream>>>(map1t, N0, mapT);
    sconv_r1<128, 64, 64><<<(N0 + 3) / 4, 256, 0, stream>>>(
        y3, y1, Wh1t, mapT, N0, y4);
    bn_reduce_h<64><<<256, 256, 0, stream>>>(y4, N0, sums4);
    bn_apply_h<64><<<512, 256, 0, stream>>>(y4, N0, sums4, g1t, b1t);

    // block0_tr: concat(d1,s1)[N0,96] -> out[N0,2] fp32
    sconv0t<<<(N0 + 7) / 8, 256, 0, stream>>>(y4, y0, W0t, map0t, N0,
                                              (float*)d_out, zrh);
}

// Round 15
// 1142.154 us; speedup vs baseline: 10.0700x; 1.0790x over previous
//
#include <hip/hip_runtime.h>
#include <cstddef>
#include <cstdint>

#define BN_EPS 1e-5f

typedef float f4 __attribute__((ext_vector_type(4)));
typedef _Float16 h2 __attribute__((ext_vector_type(2)));
typedef _Float16 h8 __attribute__((ext_vector_type(8)));

#if defined(__has_builtin)
#if __has_builtin(__builtin_amdgcn_fdot2)
#define DOT2(a, b, c) __builtin_amdgcn_fdot2((a), (b), (c), false)
#endif
#endif
#ifndef DOT2
#define DOT2(a, b, c) fmaf((float)(a)[1], (float)(b)[1], fmaf((float)(a)[0], (float)(b)[0], (c)))
#endif

// ---------------------------------------------------------------------------
// fp32 weight transpose (sconv0 only): W[27][CIN][COUT] -> Wt[k][ci/4][co][4]
// ---------------------------------------------------------------------------
template<int CIN, int COUT>
__global__ __launch_bounds__(256)
void wtrans(const float* __restrict__ W, float* __restrict__ Wt)
{
    const int t = blockIdx.x * 256 + threadIdx.x;
    constexpr int TOTAL = 27 * (CIN / 4) * COUT;
    if (t >= TOTAL) return;
    const int co = t % COUT;
    const int rest = t / COUT;
    const int c4 = rest % (CIN / 4);
    const int k  = rest / (CIN / 4);
    f4 v;
    #pragma unroll
    for (int u = 0; u < 4; ++u)
        v[u] = W[((size_t)k * CIN + c4 * 4 + u) * COUT + co];
    *(f4*)(Wt + (size_t)t * 4) = v;
}

// ---------------------------------------------------------------------------
// f16 weight transpose: W[27][CIN][COUT] -> Wh[k][ci/8][co][8]
// ---------------------------------------------------------------------------
template<int CIN, int COUT>
__global__ __launch_bounds__(256)
void wtrans_h(const float* __restrict__ W, _Float16* __restrict__ Wh)
{
    const int t = blockIdx.x * 256 + threadIdx.x;
    constexpr int TOTAL = 27 * (CIN / 8) * COUT;
    if (t >= TOTAL) return;
    const int co = t % COUT;
    const int rest = t / COUT;
    const int t8 = rest % (CIN / 8);
    const int k  = rest / (CIN / 8);
    h8 v;
    #pragma unroll
    for (int u = 0; u < 8; ++u)
        v[u] = (_Float16)W[((size_t)k * CIN + t8 * 8 + u) * COUT + co];
    *(h8*)(Wh + (size_t)t * 8) = v;
}

// ---------------------------------------------------------------------------
// Map transpose: map[27][Nout] -> mapT[Nout][32] (k-major per row, -1 pad).
// ---------------------------------------------------------------------------
__global__ __launch_bounds__(256)
void map_transpose(const int* __restrict__ map, int Nout,
                   int* __restrict__ mapT)
{
    __shared__ int s[256][28];
    const int tid  = threadIdx.x;
    const int base = blockIdx.x * 256;
    const int j    = base + tid;
    for (int k = 0; k < 27; ++k)
        s[tid][k] = (j < Nout) ? map[(size_t)k * Nout + j] : -1;
    __syncthreads();
    for (int i = tid; i < 256 * 32; i += 256) {
        const int r = i >> 5, c = i & 31;
        if (base + r < Nout)
            mapT[(size_t)(base + r) * 32 + c] = (c < 27) ? s[r][c] : -1;
    }
}

// ---------------------------------------------------------------------------
// R=1 f16 sparse conv (SPARSE maps): one wave = one row.
// ---------------------------------------------------------------------------
template<int CIN, int CINA, int COUT>
__global__ __launch_bounds__(256)
void sconv_r1(const _Float16* __restrict__ xA, const _Float16* __restrict__ xB,
              const _Float16* __restrict__ Wh, const int* __restrict__ mapT,
              int Nout, _Float16* __restrict__ out)
{
    constexpr int CINB = CIN - CINA;
    constexpr int CPL  = COUT / 64;
    constexpr int NT   = CIN / 8;
    const int lane = threadIdx.x & 63;
    const int j    = blockIdx.x * 4 + (threadIdx.x >> 6);

    int mk = -1;
    if (j < Nout && lane < 32) mk = mapT[(size_t)j * 32 + lane];
    unsigned long long act = __ballot(mk >= 0);   // bits 0..26 only

    float acc[CPL];
    #pragma unroll
    for (int c = 0; c < CPL; ++c) acc[c] = 0.f;

    while (act) {
        const int k = (int)__builtin_ctzll(act);
        act &= act - 1;
        const int m = __builtin_amdgcn_readlane(mk, k);   // uniform SGPR

        const _Float16* pA = xA + (size_t)m * CINA;
        const _Float16* pB = nullptr;
        if constexpr (CINB > 0) pB = xB + (size_t)m * CINB;

        const _Float16* Wk = Wh + (size_t)k * NT * COUT * 8;

        #pragma unroll
        for (int t = 0; t < NT; ++t) {
            const int ci = t * 8;
            h8 wv[CPL];
            #pragma unroll
            for (int c = 0; c < CPL; ++c)
                wv[c] = *(const h8*)(Wk + ((size_t)t * COUT + c * 64 + lane) * 8);
            const _Float16* p;
            if constexpr (CINB > 0)
                p = (ci < CINA) ? (pA + ci) : (pB + (ci - CINA));
            else
                p = pA + ci;
            const h8 xv = *(const h8*)p;
            const h2* xp = (const h2*)&xv;
            #pragma unroll
            for (int q = 0; q < 4; ++q) {
                #pragma unroll
                for (int c = 0; c < CPL; ++c) {
                    const h2* wp = (const h2*)&wv[c];
                    acc[c] = DOT2(xp[q], wp[q], acc[c]);
                }
            }
        }
    }

    if (j < Nout) {
        #pragma unroll
        for (int c = 0; c < CPL; ++c)
            out[(size_t)j * COUT + c * 64 + lane] = (_Float16)acc[c];
    }
}

// ---------------------------------------------------------------------------
// R-rows/wave f16 sparse conv (DENSE/MID maps), round-15 LOOP INVERSION:
// per active k, the ENTIRE W k-slice is preloaded into registers (NT*CPL
// h8 = 64 VGPRs; round-14 showed VGPR_Count=16 -- huge headroom), then rows
// loop OUTSIDE the tile loop: ONE guard per row (was R*NT branches/k-step),
// x s_loads inside the guard (invalid rows skip them -- was ~66% zrh waste),
// 16 batched s_loads then the dot2 block (the proven r1 pattern).
// ---------------------------------------------------------------------------
template<int CIN, int CINA, int COUT, int R>
__global__ __launch_bounds__(256)
void sconv_big_h(const _Float16* __restrict__ xA, const _Float16* __restrict__ xB,
                 const _Float16* __restrict__ Wh, const int* __restrict__ map,
                 int Nout, _Float16* __restrict__ out)
{
    constexpr int CINB = CIN - CINA;
    constexpr int CPL  = COUT / 64;
    constexpr int NT   = CIN / 8;
    const int lane = threadIdx.x & 63;
    const int wave = threadIdx.x >> 6;
    const int row0 = (blockIdx.x * 4 + wave) * R;

    int mk[R];
    bool anyv = false;
    #pragma unroll
    for (int r = 0; r < R; ++r) {
        const int j = row0 + r;
        mk[r] = (lane < 27 && j < Nout) ? map[(size_t)lane * Nout + j] : -1;
        anyv |= (mk[r] >= 0);
    }
    unsigned long long act = __ballot(anyv);

    float acc[R][CPL];
    #pragma unroll
    for (int r = 0; r < R; ++r)
        #pragma unroll
        for (int c = 0; c < CPL; ++c) acc[r][c] = 0.f;

    while (act) {
        const int k = (int)__builtin_ctzll(act);
        act &= act - 1;

        // ---- preload the full W k-slice into registers (64 VGPRs) ----
        const _Float16* Wk = Wh + (size_t)k * NT * COUT * 8;
        h8 wv[NT][CPL];
        #pragma unroll
        for (int t = 0; t < NT; ++t)
            #pragma unroll
            for (int c = 0; c < CPL; ++c)
                wv[t][c] = *(const h8*)(Wk + ((size_t)t * COUT + c * 64 + lane) * 8);

        // ---- per row: one guard, batched s_loads, dot2 block ----
        #pragma unroll
        for (int r = 0; r < R; ++r) {
            const int m = __builtin_amdgcn_readlane(mk[r], k);  // uniform SGPR
            if (m >= 0) {
                h8 xv[NT];
                #pragma unroll
                for (int t = 0; t < NT; ++t) {
                    const int ci = t * 8;
                    const _Float16* p;
                    if constexpr (CINB > 0)
                        p = (ci < CINA) ? (xA + (size_t)m * CINA + ci)
                                        : (xB + (size_t)m * CINB + (ci - CINA));
                    else
                        p = xA + (size_t)m * CINA + ci;
                    xv[t] = *(const h8*)p;
                }
                #pragma unroll
                for (int t = 0; t < NT; ++t) {
                    const h2* xp = (const h2*)&xv[t];
                    #pragma unroll
                    for (int q = 0; q < 4; ++q) {
                        #pragma unroll
                        for (int c = 0; c < CPL; ++c) {
                            const h2* wp = (const h2*)&wv[t][c];
                            acc[r][c] = DOT2(xp[q], wp[q], acc[r][c]);
                        }
                    }
                }
            }
        }
    }

    #pragma unroll
    for (int r = 0; r < R; ++r) {
        const int j = row0 + r;
        if (j < Nout) {
            #pragma unroll
            for (int c = 0; c < CPL; ++c)
                out[(size_t)j * COUT + c * 64 + lane] = (_Float16)acc[r][c];
        }
    }
}

// ---------------------------------------------------------------------------
// conv0: CIN=16 (fp32 feats), COUT=32 -> half out. 2 rows/wave, ctz-union.
// ---------------------------------------------------------------------------
__global__ __launch_bounds__(256)
void sconv0(const float* __restrict__ x, const float* __restrict__ Wt,
            const int* __restrict__ map, int N, _Float16* __restrict__ out,
            const float* __restrict__ zrow)
{
    const int tid  = threadIdx.x;
    const int lane = tid & 63;
    const int l32  = tid & 31;
    const int co   = l32;
    const int j    = blockIdx.x * 8 + (tid >> 5);

    int mk = (l32 < 27 && j < N) ? map[(size_t)l32 * N + j] : -1;
    const unsigned long long bal = __ballot(mk >= 0);
    unsigned int act = (unsigned int)((bal | (bal >> 32)) & 0x7FFFFFFu);

    float a0 = 0.f, a1 = 0.f, a2 = 0.f, a3 = 0.f;
    while (act) {
        const int k = (int)__builtin_ctz(act);
        act &= act - 1;
        const int m = __shfl(mk, (lane & 32) + k);
        const float* xr = (m >= 0) ? (x + (size_t)m * 16) : zrow;
        const float* wk = Wt + (size_t)k * 16 * 32;
        f4 w0 = *(const f4*)(wk + (0 * 32 + co) * 4);
        f4 w1 = *(const f4*)(wk + (1 * 32 + co) * 4);
        f4 w2 = *(const f4*)(wk + (2 * 32 + co) * 4);
        f4 w3 = *(const f4*)(wk + (3 * 32 + co) * 4);
        f4 x0 = *(const f4*)(xr);
        f4 x1 = *(const f4*)(xr + 4);
        f4 x2 = *(const f4*)(xr + 8);
        f4 x3 = *(const f4*)(xr + 12);
        #pragma unroll
        for (int u = 0; u < 4; ++u) {
            a0 = fmaf(x0[u], w0[u], a0);
            a1 = fmaf(x1[u], w1[u], a1);
            a2 = fmaf(x2[u], w2[u], a2);
            a3 = fmaf(x3[u], w3[u], a3);
        }
    }
    if (j < N) out[(size_t)j * 32 + co] = (_Float16)((a0 + a1) + (a2 + a3));
}

// ---------------------------------------------------------------------------
// conv0t: concat(d1[*,64]h, s1[*,32]h) -> out[N0,2] fp32. ctz-union loop.
// ---------------------------------------------------------------------------
__global__ __launch_bounds__(256)
void sconv0t(const _Float16* __restrict__ d1, const _Float16* __restrict__ s1,
             const float* __restrict__ W /*[27,96,2]*/,
             const int* __restrict__ map, int N, float* __restrict__ out,
             const _Float16* __restrict__ zrh)
{
    const int tid  = threadIdx.x;
    const int lane = tid & 63;
    const int l32  = tid & 31;
    const int j    = blockIdx.x * 8 + (tid >> 5);

    int mk = (l32 < 27 && j < N) ? map[(size_t)l32 * N + j] : -1;
    const unsigned long long bal = __ballot(mk >= 0);
    unsigned int act = (unsigned int)((bal | (bal >> 32)) & 0x7FFFFFFu);

    float a0 = 0.f, a1 = 0.f;
    while (act) {
        const int k = (int)__builtin_ctz(act);
        act &= act - 1;
        const int m = __shfl(mk, (lane & 32) + k);
        const _Float16* p1 = (m >= 0) ? (d1 + (size_t)m * 64) : zrh;
        const _Float16* p2 = (m >= 0) ? (s1 + (size_t)m * 32) : zrh;
        const float* w = W + (size_t)k * 96 * 2;
        const float x0 = (float)p1[l32];
        const float x1 = (float)p1[l32 + 32];
        const float x2 = (float)p2[l32];
        a0 = fmaf(x0, w[l32 * 2 + 0], a0);
        a1 = fmaf(x0, w[l32 * 2 + 1], a1);
        a0 = fmaf(x1, w[(l32 + 32) * 2 + 0], a0);
        a1 = fmaf(x1, w[(l32 + 32) * 2 + 1], a1);
        a0 = fmaf(x2, w[(l32 + 64) * 2 + 0], a0);
        a1 = fmaf(x2, w[(l32 + 64) * 2 + 1], a1);
    }
    #pragma unroll
    for (int off = 1; off < 32; off <<= 1) {
        a0 += __shfl_xor(a0, off, 32);
        a1 += __shfl_xor(a1, off, 32);
    }
    if (l32 == 0 && j < N) {
        out[(size_t)j * 2 + 0] = a0;
        out[(size_t)j * 2 + 1] = a1;
    }
}

// ---------------------------------------------------------------------------
// BN pass 1 on half tensors
// ---------------------------------------------------------------------------
template<int C>
__global__ __launch_bounds__(256)
void bn_reduce_h(const _Float16* __restrict__ x, int N,
                 float* __restrict__ sums)
{
    constexpr int RG = 256 / C;
    const int tid = threadIdx.x;
    const int c   = tid % C;
    const int rg  = tid / C;
    float s = 0.f, s2 = 0.f;
    for (int j = blockIdx.x * RG + rg; j < N; j += gridDim.x * RG) {
        const float v = (float)x[(size_t)j * C + c];
        s += v;
        s2 += v * v;
    }
    __shared__ float sh[2 * 256];
    sh[tid] = s;
    sh[256 + tid] = s2;
    __syncthreads();
    for (int stride = 128; stride >= C; stride >>= 1) {
        if (tid < stride) {
            sh[tid] += sh[tid + stride];
            sh[256 + tid] += sh[256 + tid + stride];
        }
        __syncthreads();
    }
    if (tid < C) {
        atomicAdd(&sums[c], sh[tid]);
        atomicAdd(&sums[C + c], sh[256 + tid]);
    }
}

// ---------------------------------------------------------------------------
// BN pass 2 on half tensors
// ---------------------------------------------------------------------------
template<int C>
__global__ __launch_bounds__(256)
void bn_apply_h(_Float16* __restrict__ x, int N,
                const float* __restrict__ sums,
                const float* __restrict__ g, const float* __restrict__ b)
{
    const int tid = blockIdx.x * blockDim.x + threadIdx.x;
    const int c = tid % C;
    const float invN = 1.0f / (float)N;
    const float mean = sums[c] * invN;
    float var = sums[C + c] * invN - mean * mean;
    var = fmaxf(var, 0.f);
    const float sc = g[c] * rsqrtf(var + BN_EPS);
    const float sh = b[c] - mean * sc;
    const int rows_stride = (gridDim.x * blockDim.x) / C;
    for (int j = tid / C; j < N; j += rows_stride) {
        const size_t i = (size_t)j * C + c;
        const float v = fmaf((float)x[i], sc, sh);
        x[i] = (_Float16)(v > 0.f ? v : 0.f);
    }
}

// ---------------------------------------------------------------------------
extern "C" void kernel_launch(void* const* d_in, const int* in_sizes, int n_in,
                              void* d_out, int out_size, void* d_ws, size_t ws_size,
                              hipStream_t stream)
{
    const float* feats = (const float*)d_in[0];
    const float* W0  = (const float*)d_in[1];
    const float* g0  = (const float*)d_in[2];
    const float* b0  = (const float*)d_in[3];
    const float* W1  = (const float*)d_in[4];
    const float* g1  = (const float*)d_in[5];
    const float* b1  = (const float*)d_in[6];
    const float* W2  = (const float*)d_in[7];
    const float* g2  = (const float*)d_in[8];
    const float* b2  = (const float*)d_in[9];
    const float* W2t = (const float*)d_in[10];
    const float* g2t = (const float*)d_in[11];
    const float* b2t = (const float*)d_in[12];
    const float* W1t = (const float*)d_in[13];
    const float* g1t = (const float*)d_in[14];
    const float* b1t = (const float*)d_in[15];
    const float* W0t = (const float*)d_in[16];
    const int* map0  = (const int*)d_in[17];
    const int* map1  = (const int*)d_in[18];
    const int* map2  = (const int*)d_in[19];
    const int* map2t = (const int*)d_in[20];
    const int* map1t = (const int*)d_in[21];
    const int* map0t = (const int*)d_in[22];

    const int N0 = in_sizes[0] / 16;
    const int N1 = in_sizes[18] / 27;
    const int N2 = in_sizes[19] / 27;

    float* ws = (float*)d_ws;
    float* sums  = ws;          // 704 floats of BN accumulators
    float* sums0 = sums;        // 2*32
    float* sums1 = sums + 64;   // 2*64
    float* sums2 = sums + 192;  // 2*128
    float* sums3 = sums + 448;  // 2*64
    float* sums4 = sums + 576;  // 2*64
    float* zrow  = sums + 704;  // 128 zeroed floats (fp32 & f16 zero rows)
    float* Wt0   = zrow + 128;  // 27*16*32 fp32
    _Float16* hb = (_Float16*)(Wt0 + 27 * 16 * 32);
    _Float16* Wh1  = hb;                        // 27*32*64
    _Float16* Wh2  = Wh1 + 27 * 32 * 64;        // 27*64*128
    _Float16* Wh2t = Wh2 + 27 * 64 * 128;       // 27*128*64
    _Float16* Wh1t = Wh2t + 27 * 128 * 64;      // 27*128*64
    _Float16* y0 = Wh1t + 27 * 128 * 64;        // [N0,32]  s1
    _Float16* y1 = y0 + (size_t)N0 * 32;        // [N1,64]  s2
    _Float16* y2 = y1 + (size_t)N1 * 64;        // [N2,128] s4
    _Float16* y3 = y2 + (size_t)N2 * 128;       // [N1,64]  d2
    _Float16* y4 = y3 + (size_t)N1 * 64;        // [N0,64]  d1
    int* mapT = (int*)(y4 + (size_t)N0 * 64);   // [Nmax,32] transposed map
    const _Float16* zrh = (const _Float16*)zrow;

    (void)hipMemsetAsync(sums, 0, (704 + 128) * sizeof(float), stream);

    // weight transposes (tiny)
    wtrans<16, 32><<<(27 * 4 * 32 + 255) / 256, 256, 0, stream>>>(W0, Wt0);
    wtrans_h<32, 64><<<(27 * 4 * 64 + 255) / 256, 256, 0, stream>>>(W1, Wh1);
    wtrans_h<64, 128><<<(27 * 8 * 128 + 255) / 256, 256, 0, stream>>>(W2, Wh2);
    wtrans_h<128, 64><<<(27 * 16 * 64 + 255) / 256, 256, 0, stream>>>(W2t, Wh2t);
    wtrans_h<128, 64><<<(27 * 16 * 64 + 255) / 256, 256, 0, stream>>>(W1t, Wh1t);

    // block0: feats[N0,16] fp32 -> y0[N0,32] half
    sconv0<<<(N0 + 7) / 8, 256, 0, stream>>>(feats, Wt0, map0, N0, y0, zrow);
    bn_reduce_h<32><<<256, 256, 0, stream>>>(y0, N0, sums0);
    bn_apply_h<32><<<512, 256, 0, stream>>>(y0, N0, sums0, g0, b0);

    // block1 (SPARSE map): one wave per row
    map_transpose<<<(N1 + 255) / 256, 256, 0, stream>>>(map1, N1, mapT);
    sconv_r1<32, 32, 64><<<(N1 + 3) / 4, 256, 0, stream>>>(
        y0, nullptr, Wh1, mapT, N1, y1);
    bn_reduce_h<64><<<256, 256, 0, stream>>>(y1, N1, sums1);
    bn_apply_h<64><<<512, 256, 0, stream>>>(y1, N1, sums1, g1, b1);

    // block2 (DENSE map ~30%): R=8 rows/wave, inverted loops
    sconv_big_h<64, 64, 128, 8><<<(N2 + 31) / 32, 256, 0, stream>>>(
        y1, nullptr, Wh2, map2, N2, y2);
    bn_reduce_h<128><<<256, 256, 0, stream>>>(y2, N2, sums2);
    bn_apply_h<128><<<512, 256, 0, stream>>>(y2, N2, sums2, g2, b2);

    // block2_tr (MID map ~12.5%): R=4 rows/wave, inverted loops
    sconv_big_h<128, 128, 64, 4><<<(N1 + 15) / 16, 256, 0, stream>>>(
        y2, nullptr, Wh2t, map2t, N1, y3);
    bn_reduce_h<64><<<256, 256, 0, stream>>>(y3, N1, sums3);
    bn_apply_h<64><<<512, 256, 0, stream>>>(y3, N1, sums3, g2t, b2t);

    // block1_tr (SPARSE map): one wave per row
    map_transpose<<<(N0 + 255) / 256, 256, 0, stream>>>(map1t, N0, mapT);
    sconv_r1<128, 64, 64><<<(N0 + 3) / 4, 256, 0, stream>>>(
        y3, y1, Wh1t, mapT, N0, y4);
    bn_reduce_h<64><<<256, 256, 0, stream>>>(y4, N0, sums4);
    bn_apply_h<64><<<512, 256, 0, stream>>>(y4, N0, sums4, g1t, b1t);

    // block0_tr: concat(d1,s1)[N0,96] -> out[N0,2] fp32
    sconv0t<<<(N0 + 7) / 8, 256, 0, stream>>>(y4, y0, W0t, map0t, N0,
                                              (float*)d_out, zrh);
}